// Round 2
// baseline (876.477 us; speedup 1.0000x reference)
//
#include <hip/hip_runtime.h>
#include <hip/hip_bf16.h>
#include <math.h>

#define NV 100000
#define NE_N 100000
#define NEDGE 250000
#define NEG 0.2f
#define LN_EPS 1e-5f

// ---------------------------------------------------------------------------
// helpers: bf16 pack/unpack (manual, RNE)
// ---------------------------------------------------------------------------
__device__ inline unsigned short f2bf(float f) {
    unsigned u = __float_as_uint(f);
    u += 0x7fffu + ((u >> 16) & 1u);
    return (unsigned short)(u >> 16);
}
__device__ inline float blo(unsigned w) { return __uint_as_float(w << 16); }
__device__ inline float bhi(unsigned w) { return __uint_as_float(w & 0xffff0000u); }
__device__ inline float lrelu(float x) { return x > 0.f ? x : NEG * x; }

// ---------------------------------------------------------------------------
// Fused encoder + projection GEMM:
//   h = LayerNorm(ReLU(feat[M,16] @ Wenc[16,128] + benc)) * g + beta   (in LDS)
//   out_bf16[M,512] = h @ Wproj[128,512] + bproj
// block: 64 rows x 128 cols, 256 threads, 8x4 fp32 accumulators.
// Encoder recomputed per column-block (cheap: K=16).
// ---------------------------------------------------------------------------
__global__ __launch_bounds__(256) void enc_proj_kernel(
    const float* __restrict__ feat,
    const float* __restrict__ Wenc, const float* __restrict__ benc,
    const float* __restrict__ g, const float* __restrict__ beta,
    const float* __restrict__ Wproj, const float* __restrict__ bproj,
    unsigned short* __restrict__ out, int M)
{
    __shared__ float As[64 * 128];     // relu/h tile
    __shared__ float Ft[64 * 16];      // feat tile
    __shared__ float red_s[256];
    __shared__ float red_q[256];
    __shared__ float s_mu[64], s_inv[64];

    int row0 = blockIdx.x * 64;
    int col0 = blockIdx.y * 128;
    int t = threadIdx.x;

    // stage feat tile (64 x 16), zero-pad past M
    for (int i = t; i < 64 * 16; i += 256) {
        int r = i >> 4;
        Ft[i] = (row0 + r < M) ? feat[(size_t)(row0 + r) * 16 + (i & 15)] : 0.f;
    }
    __syncthreads();

    // encoder matmul + relu: thread owns col (t&127), rows 2i + (t>>7)
    int colh = t & 127;
    int rof = t >> 7;
    {
        float wcol[16];
#pragma unroll
        for (int k = 0; k < 16; ++k) wcol[k] = Wenc[k * 128 + colh];
        float bcol = benc[colh];
#pragma unroll
        for (int i = 0; i < 32; ++i) {
            int r = 2 * i + rof;
            float acc = bcol;
#pragma unroll
            for (int k = 0; k < 16; ++k)
                acc = fmaf(Ft[r * 16 + k], wcol[k], acc);
            As[r * 128 + colh] = fmaxf(acc, 0.f);
        }
    }
    __syncthreads();

    // layernorm stats: row = t>>2, quad (t&3) sums 32 cols
    {
        int r = t >> 2, q = t & 3;
        float s = 0.f, s2 = 0.f;
#pragma unroll
        for (int c = q * 32; c < q * 32 + 32; ++c) {
            float v = As[r * 128 + c];
            s += v;
            s2 = fmaf(v, v, s2);
        }
        red_s[t] = s;
        red_q[t] = s2;
    }
    __syncthreads();
    if (t < 64) {
        float s  = red_s[t * 4] + red_s[t * 4 + 1] + red_s[t * 4 + 2] + red_s[t * 4 + 3];
        float s2 = red_q[t * 4] + red_q[t * 4 + 1] + red_q[t * 4 + 2] + red_q[t * 4 + 3];
        float mu = s * (1.f / 128.f);
        float var = s2 * (1.f / 128.f) - mu * mu;
        s_mu[t] = mu;
        s_inv[t] = rsqrtf(var + LN_EPS);
    }
    __syncthreads();
    // normalize in place
    {
        float gc = g[colh], bc = beta[colh];
#pragma unroll
        for (int i = 0; i < 32; ++i) {
            int r = 2 * i + rof;
            As[r * 128 + colh] = (As[r * 128 + colh] - s_mu[r]) * s_inv[r] * gc + bc;
        }
    }
    __syncthreads();

    // projection GEMM: 8 rows x 4 cols per thread
    int cg = t & 31;
    int rg = t >> 5;
    int col = col0 + cg * 4;
    int rbase = rg * 8;

    float acc[8][4];
#pragma unroll
    for (int r = 0; r < 8; ++r)
#pragma unroll
        for (int c = 0; c < 4; ++c) acc[r][c] = 0.f;

#pragma unroll 4
    for (int k = 0; k < 128; ++k) {
        float4 bv = *(const float4*)(Wproj + (size_t)k * 512 + col);
#pragma unroll
        for (int r = 0; r < 8; ++r) {
            float a = As[(rbase + r) * 128 + k];
            acc[r][0] = fmaf(a, bv.x, acc[r][0]);
            acc[r][1] = fmaf(a, bv.y, acc[r][1]);
            acc[r][2] = fmaf(a, bv.z, acc[r][2]);
            acc[r][3] = fmaf(a, bv.w, acc[r][3]);
        }
    }

    float4 bb = *(const float4*)(bproj + col);
#pragma unroll
    for (int r = 0; r < 8; ++r) {
        int row = row0 + rbase + r;
        if (row < M) {
            ushort4 o;
            o.x = f2bf(acc[r][0] + bb.x);
            o.y = f2bf(acc[r][1] + bb.y);
            o.z = f2bf(acc[r][2] + bb.z);
            o.w = f2bf(acc[r][3] + bb.w);
            *(ushort4*)(out + (size_t)row * 512 + col) = o;
        }
    }
}

// ---------------------------------------------------------------------------
// plain fp32 GEMM (final projection, in-place safe: tile staged before write)
//   C[M,128] = relu(A[M,128] @ W[128,128] + bias)
// ---------------------------------------------------------------------------
__global__ __launch_bounds__(256) void final_gemm_kernel(
    const float* __restrict__ A, const float* __restrict__ W,
    const float* __restrict__ bias, float* __restrict__ C, int M)
{
    __shared__ float As[64 * 128];
    int row0 = blockIdx.x * 64;
    int t = threadIdx.x;

#pragma unroll
    for (int i = 0; i < 8; ++i) {
        int f4 = i * 256 + t;
        int r = f4 >> 5;
        float4 v = make_float4(0.f, 0.f, 0.f, 0.f);
        if (row0 + r < M)
            v = ((const float4*)(A + (size_t)(row0 + r) * 128))[f4 & 31];
        ((float4*)As)[f4] = v;
    }
    __syncthreads();

    int cg = t & 31;
    int rg = t >> 5;
    int col = cg * 4;
    int rbase = rg * 8;

    float acc[8][4];
#pragma unroll
    for (int r = 0; r < 8; ++r)
#pragma unroll
        for (int c = 0; c < 4; ++c) acc[r][c] = 0.f;

#pragma unroll 4
    for (int k = 0; k < 128; ++k) {
        float4 bv = *(const float4*)(W + (size_t)k * 128 + col);
#pragma unroll
        for (int r = 0; r < 8; ++r) {
            float a = As[(rbase + r) * 128 + k];
            acc[r][0] = fmaf(a, bv.x, acc[r][0]);
            acc[r][1] = fmaf(a, bv.y, acc[r][1]);
            acc[r][2] = fmaf(a, bv.z, acc[r][2]);
            acc[r][3] = fmaf(a, bv.w, acc[r][3]);
        }
    }

    float4 bb = *(const float4*)(bias + col);
#pragma unroll
    for (int r = 0; r < 8; ++r) {
        int row = row0 + rbase + r;
        if (row < M) {
            float4 o;
            o.x = fmaxf(acc[r][0] + bb.x, 0.f);
            o.y = fmaxf(acc[r][1] + bb.y, 0.f);
            o.z = fmaxf(acc[r][2] + bb.z, 0.f);
            o.w = fmaxf(acc[r][3] + bb.w, 0.f);
            *(float4*)(C + (size_t)row * 128 + col) = o;
        }
    }
}

// ---------------------------------------------------------------------------
// order-preserving float<->uint mapping (0 == "-inf" sentinel)
// ---------------------------------------------------------------------------
__device__ inline unsigned ford(float f) {
    int b = __float_as_int(f);
    return (b >= 0) ? ((unsigned)b | 0x80000000u) : (unsigned)(~b);
}
__device__ inline float fdec(unsigned u) {
    int b = (u & 0x80000000u) ? (int)(u & 0x7FFFFFFFu) : ~((int)u);
    return __int_as_float(b);
}

// ---------------------------------------------------------------------------
// score: per (edge, head): sum_d lrelu(fs[src]+fd[dst]) * attn ; segment max
// one wave per edge; lane owns 8 contiguous bf16 elements (16 lanes per head)
// ---------------------------------------------------------------------------
__global__ __launch_bounds__(256) void score_kernel(
    const unsigned short* __restrict__ fs, const unsigned short* __restrict__ fd,
    const float* __restrict__ attn, const int* __restrict__ src,
    const int* __restrict__ dst, float* __restrict__ score,
    unsigned* __restrict__ smax)
{
    int e = blockIdx.x * 4 + (threadIdx.x >> 6);
    if (e >= NEDGE) return;
    int l = threadIdx.x & 63;
    int s = src[e];
    int d = dst[e];
    int o = l * 8;

    uint4 a = *(const uint4*)(fs + (size_t)s * 512 + o);
    uint4 b = *(const uint4*)(fd + (size_t)d * 512 + o);
    float4 w0 = *(const float4*)(attn + o);
    float4 w1 = *(const float4*)(attn + o + 4);

    float p = 0.f;
    p = fmaf(lrelu(blo(a.x) + blo(b.x)), w0.x, p);
    p = fmaf(lrelu(bhi(a.x) + bhi(b.x)), w0.y, p);
    p = fmaf(lrelu(blo(a.y) + blo(b.y)), w0.z, p);
    p = fmaf(lrelu(bhi(a.y) + bhi(b.y)), w0.w, p);
    p = fmaf(lrelu(blo(a.z) + blo(b.z)), w1.x, p);
    p = fmaf(lrelu(bhi(a.z) + bhi(b.z)), w1.y, p);
    p = fmaf(lrelu(blo(a.w) + blo(b.w)), w1.z, p);
    p = fmaf(lrelu(bhi(a.w) + bhi(b.w)), w1.w, p);

#pragma unroll
    for (int m = 1; m < 16; m <<= 1)
        p += __shfl_xor(p, m, 64);

    if ((l & 15) == 0) {
        int h = l >> 4;
        score[e * 4 + h] = p;
        atomicMax(&smax[d * 4 + h], ford(p));
    }
}

// ---------------------------------------------------------------------------
// softmax numerator (in place) + denominator
// ---------------------------------------------------------------------------
__global__ __launch_bounds__(256) void softmax_kernel(
    const int* __restrict__ dst, float* __restrict__ score_ex,
    const unsigned* __restrict__ smax, float* __restrict__ denom)
{
    int t = blockIdx.x * 256 + threadIdx.x;
    if (t >= NEDGE * 4) return;
    int e = t >> 2, h = t & 3;
    int d = dst[e];
    float m = fdec(smax[d * 4 + h]);
    float ex = __expf(score_ex[t] - m);
    score_ex[t] = ex;
    atomicAdd(&denom[d * 4 + h], ex);
}

// ---------------------------------------------------------------------------
// aggregate: edge_out[dst] += sum_h alpha[e,h]*0.25 * fs[src, h, :]
// one wave per edge, lane owns 2 d-values; heads reduced in-register
// ---------------------------------------------------------------------------
__global__ __launch_bounds__(256) void aggregate_kernel(
    const unsigned short* __restrict__ fs, const float* __restrict__ ex,
    const float* __restrict__ denom, const int* __restrict__ src,
    const int* __restrict__ dst, float* __restrict__ edge_out)
{
    int e = blockIdx.x * 4 + (threadIdx.x >> 6);
    if (e >= NEDGE) return;
    int l = threadIdx.x & 63;
    int s = src[e];
    int d = dst[e];

    float alpha[4];
#pragma unroll
    for (int h = 0; h < 4; ++h)
        alpha[h] = ex[e * 4 + h] / denom[d * 4 + h] * 0.25f;

    int o = l * 2;
    float v0 = 0.f, v1 = 0.f;
#pragma unroll
    for (int h = 0; h < 4; ++h) {
        unsigned w = *(const unsigned*)(fs + (size_t)s * 512 + h * 128 + o);
        v0 = fmaf(alpha[h], blo(w), v0);
        v1 = fmaf(alpha[h], bhi(w), v1);
    }
    atomicAdd(&edge_out[(size_t)d * 128 + o], v0);
    atomicAdd(&edge_out[(size_t)d * 128 + o + 1], v1);
}

// ---------------------------------------------------------------------------
extern "C" void kernel_launch(void* const* d_in, const int* in_sizes, int n_in,
                              void* d_out, int out_size, void* d_ws, size_t ws_size,
                              hipStream_t stream)
{
    const float* v_feat = (const float*)d_in[0];
    const float* e_feat = (const float*)d_in[1];
    const float* Wv     = (const float*)d_in[2];
    const float* bv     = (const float*)d_in[3];
    const float* gv     = (const float*)d_in[4];
    const float* betav  = (const float*)d_in[5];
    const float* We     = (const float*)d_in[6];
    const float* be     = (const float*)d_in[7];
    const float* ge     = (const float*)d_in[8];
    const float* betae  = (const float*)d_in[9];
    const float* Wsrc   = (const float*)d_in[10];
    const float* bsrc   = (const float*)d_in[11];
    const float* Wdst   = (const float*)d_in[12];
    const float* bdst   = (const float*)d_in[13];
    const float* attn   = (const float*)d_in[14];
    const float* Wp     = (const float*)d_in[15];
    const float* bp     = (const float*)d_in[16];
    const int*   src    = (const int*)d_in[17];
    const int*   dst    = (const int*)d_in[18];
    float* out = (float*)d_out;

    // workspace layout (bytes): fs 102.4M | fd 102.4M | ex 4M | smax 1.6M |
    // denom 1.6M  => total ~211.6 MB.  edge_out accumulates in d_out.
    unsigned short* fs = (unsigned short*)d_ws;
    unsigned short* fd = fs + (size_t)NV * 512;
    float* exb   = (float*)(fd + (size_t)NE_N * 512);
    unsigned* smax = (unsigned*)(exb + (size_t)NEDGE * 4);
    float* denom = (float*)(smax + (size_t)NE_N * 4);

    dim3 gproj(1563, 4);
    enc_proj_kernel<<<gproj, 256, 0, stream>>>(v_feat, Wv, bv, gv, betav,
                                               Wsrc, bsrc, fs, NV);
    enc_proj_kernel<<<gproj, 256, 0, stream>>>(e_feat, We, be, ge, betae,
                                               Wdst, bdst, fd, NE_N);

    hipMemsetAsync(smax, 0, (size_t)NE_N * 4 * sizeof(unsigned), stream);
    hipMemsetAsync(denom, 0, (size_t)NE_N * 4 * sizeof(float), stream);
    hipMemsetAsync(out, 0, (size_t)NE_N * 128 * sizeof(float), stream);

    score_kernel<<<NEDGE / 4, 256, 0, stream>>>(fs, fd, attn, src, dst, exb, smax);
    softmax_kernel<<<(NEDGE * 4 + 255) / 256, 256, 0, stream>>>(dst, exb, smax, denom);
    aggregate_kernel<<<NEDGE / 4, 256, 0, stream>>>(fs, exb, denom, src, dst, out);

    final_gemm_kernel<<<1563, 256, 0, stream>>>(out, Wp, bp, out, NE_N);
}

// Round 3
// 774.977 us; speedup vs baseline: 1.1310x; 1.1310x over previous
//
#include <hip/hip_runtime.h>
#include <hip/hip_bf16.h>
#include <math.h>

#define NV 100000
#define NE_N 100000
#define NEDGE 250000
#define NEG 0.2f
#define LN_EPS 1e-5f

typedef __bf16 bf16_t;
typedef __bf16 bf16x8 __attribute__((ext_vector_type(8)));
typedef float f32x4 __attribute__((ext_vector_type(4)));

__device__ inline unsigned short f2bfu(float f) {
    return __builtin_bit_cast(unsigned short, (__bf16)f);
}
__device__ inline float bfu2f(unsigned short u) {
    return (float)__builtin_bit_cast(__bf16, u);
}
__device__ inline float blo(unsigned w) { return __uint_as_float(w << 16); }
__device__ inline float bhi(unsigned w) { return __uint_as_float(w & 0xffff0000u); }
__device__ inline float lrelu(float x) { return x > 0.f ? x : NEG * x; }

// ---------------------------------------------------------------------------
// prep: pack W matrices into bf16 A-fragment order:
//   pack[((ksq)*N + col)*8 + j] = W[ksq*8 + j][col],  ksq = 0..15 (K=128)
// groups: Wsrc 16*512, Wdst 16*512, Wp 16*128
// ---------------------------------------------------------------------------
__global__ __launch_bounds__(256) void prep_kernel(
    const float* __restrict__ Wsrc, const float* __restrict__ Wdst,
    const float* __restrict__ Wp, bf16_t* __restrict__ pS,
    bf16_t* __restrict__ pD, bf16_t* __restrict__ pP)
{
    int t = blockIdx.x * 256 + threadIdx.x;
    if (t < 8192) {
        int ksq = t >> 9, col = t & 511;
#pragma unroll
        for (int j = 0; j < 8; ++j)
            pS[(size_t)t * 8 + j] = (bf16_t)Wsrc[(ksq * 8 + j) * 512 + col];
    } else if (t < 16384) {
        int g = t - 8192;
        int ksq = g >> 9, col = g & 511;
#pragma unroll
        for (int j = 0; j < 8; ++j)
            pD[(size_t)g * 8 + j] = (bf16_t)Wdst[(ksq * 8 + j) * 512 + col];
    } else if (t < 18432) {
        int g = t - 16384;
        int ksq = g >> 7, col = g & 127;
#pragma unroll
        for (int j = 0; j < 8; ++j)
            pP[(size_t)g * 8 + j] = (bf16_t)Wp[(ksq * 8 + j) * 128 + col];
    }
}

// ---------------------------------------------------------------------------
// Fused encoder + MFMA projection:
//   h = LayerNorm(ReLU(feat[M,16] @ Wenc[16,128] + benc)) * g + beta (bf16 LDS)
//   out_bf16[M,512] = h @ Wproj + bproj   via mfma_f32_16x16x32_bf16
// A-operand = packed W^T (m = output col), B-operand = h (n = node row).
// 64 rows x 512 cols per block, 256 threads (wave w owns cols w*128..+127).
// ---------------------------------------------------------------------------
__global__ __launch_bounds__(256) void enc_proj_kernel(
    const float* __restrict__ feat,
    const float* __restrict__ Wenc, const float* __restrict__ benc,
    const float* __restrict__ g, const float* __restrict__ beta,
    const bf16_t* __restrict__ Apack, const float* __restrict__ bproj,
    unsigned short* __restrict__ out, int M)
{
    __shared__ unsigned short Hs[64 * 136];   // h tile, bf16, stride 136 (pad 8)
    __shared__ float red_s[256], red_q[256];
    __shared__ float s_mu[64], s_inv[64];

    int t = threadIdx.x;
    int lane = t & 63;
    int w = t >> 6;
    int row0 = blockIdx.x * 64;

    // ---- encoder: thread owns col, 32 rows (stride 2); feat via scalar loads
    int colE = (w & 1) * 64 + lane;
    float wcol[16];
#pragma unroll
    for (int k = 0; k < 16; ++k) wcol[k] = Wenc[k * 128 + colE];
    float bcol = benc[colE];
    int rof = __builtin_amdgcn_readfirstlane(t >> 7);

    float vals[32];
#pragma unroll
    for (int i = 0; i < 32; ++i) {
        int r = 2 * i + rof;
        int grow = row0 + r;
        if (grow >= M) grow = M - 1;              // wave-uniform clamp
        const float* fr = feat + (size_t)grow * 16;
        float acc = bcol;
#pragma unroll
        for (int k = 0; k < 16; ++k)
            acc = fmaf(fr[k], wcol[k], acc);
        acc = fmaxf(acc, 0.f);
        vals[i] = acc;
        Hs[r * 136 + colE] = f2bfu(acc);          // pre-LN copy for stats
    }
    __syncthreads();

    // ---- layernorm stats (on bf16-rounded relu values)
    {
        int r = t >> 2, q = t & 3;
        float s = 0.f, s2 = 0.f;
#pragma unroll
        for (int c = q * 32; c < q * 32 + 32; ++c) {
            float v = bfu2f(Hs[r * 136 + c]);
            s += v;
            s2 = fmaf(v, v, s2);
        }
        red_s[t] = s;
        red_q[t] = s2;
    }
    __syncthreads();
    if (t < 64) {
        float s  = red_s[t * 4] + red_s[t * 4 + 1] + red_s[t * 4 + 2] + red_s[t * 4 + 3];
        float s2 = red_q[t * 4] + red_q[t * 4 + 1] + red_q[t * 4 + 2] + red_q[t * 4 + 3];
        float mu = s * (1.f / 128.f);
        float var = s2 * (1.f / 128.f) - mu * mu;
        s_mu[t] = mu;
        s_inv[t] = rsqrtf(var + LN_EPS);
    }
    __syncthreads();

    // ---- normalize from registers, rewrite Hs as final bf16 h
    {
        float gc = g[colE], bc = beta[colE];
#pragma unroll
        for (int i = 0; i < 32; ++i) {
            int r = 2 * i + rof;
            float nv = (vals[i] - s_mu[r]) * s_inv[r] * gc + bc;
            Hs[r * 136 + colE] = f2bfu(nv);
        }
    }
    __syncthreads();

    // ---- MFMA: wave w computes 64 rows x 128 cols (8 m-tiles x 4 n-tiles)
    int kq = lane >> 4;
    int ln = lane & 15;
    int wcol0 = w * 128;

    f32x4 acc[8][4];
#pragma unroll
    for (int mt = 0; mt < 8; ++mt)
#pragma unroll
        for (int nt = 0; nt < 4; ++nt) {
            f32x4 z = {0.f, 0.f, 0.f, 0.f};
            acc[mt][nt] = z;
        }

#pragma unroll
    for (int ks = 0; ks < 4; ++ks) {
        bf16x8 bfr[4];
#pragma unroll
        for (int nt = 0; nt < 4; ++nt) {
            const uint4* p = (const uint4*)&Hs[(nt * 16 + ln) * 136 + ks * 32 + kq * 8];
            bfr[nt] = __builtin_bit_cast(bf16x8, *p);
        }
        bf16x8 afr[8];
#pragma unroll
        for (int mt = 0; mt < 8; ++mt) {
            int colA = wcol0 + mt * 16 + ln;
            afr[mt] = *(const bf16x8*)(Apack + ((size_t)(ks * 4 + kq) * 512 + colA) * 8);
        }
#pragma unroll
        for (int mt = 0; mt < 8; ++mt)
#pragma unroll
            for (int nt = 0; nt < 4; ++nt)
                acc[mt][nt] = __builtin_amdgcn_mfma_f32_16x16x32_bf16(
                    afr[mt], bfr[nt], acc[mt][nt], 0, 0, 0);
    }

    // ---- epilogue: lane holds 4 consecutive output cols for node row
#pragma unroll
    for (int mt = 0; mt < 8; ++mt) {
        int col = wcol0 + mt * 16 + kq * 4;
        float4 bb = *(const float4*)(bproj + col);
#pragma unroll
        for (int nt = 0; nt < 4; ++nt) {
            int node = row0 + nt * 16 + ln;
            if (node < M) {
                ushort4 o;
                o.x = f2bfu(acc[mt][nt][0] + bb.x);
                o.y = f2bfu(acc[mt][nt][1] + bb.y);
                o.z = f2bfu(acc[mt][nt][2] + bb.z);
                o.w = f2bfu(acc[mt][nt][3] + bb.w);
                *(ushort4*)(out + (size_t)node * 512 + col) = o;
            }
        }
    }
}

// ---------------------------------------------------------------------------
// final GEMM (MFMA): C[M,128] = relu(A[M,128] @ Wp + bp), in place (A == C)
// ---------------------------------------------------------------------------
__global__ __launch_bounds__(256) void final_gemm_kernel(
    const float* __restrict__ A, const bf16_t* __restrict__ Ppack,
    const float* __restrict__ bp, float* __restrict__ C, int M)
{
    __shared__ unsigned short Hs[64 * 136];
    int t = threadIdx.x;
    int lane = t & 63;
    int w = t >> 6;
    int row0 = blockIdx.x * 64;

    // stage 64x128 fp32 -> bf16 LDS (padded stride)
#pragma unroll
    for (int i = 0; i < 8; ++i) {
        int f4 = i * 256 + t;
        int r = f4 >> 5;
        int c4 = (f4 & 31) * 4;
        float4 v = make_float4(0.f, 0.f, 0.f, 0.f);
        if (row0 + r < M)
            v = ((const float4*)(A + (size_t)(row0 + r) * 128))[f4 & 31];
        ushort4 o;
        o.x = f2bfu(v.x); o.y = f2bfu(v.y); o.z = f2bfu(v.z); o.w = f2bfu(v.w);
        *(ushort4*)&Hs[r * 136 + c4] = o;
    }
    __syncthreads();

    int kq = lane >> 4;
    int ln = lane & 15;

    f32x4 acc[2][4];
#pragma unroll
    for (int mt = 0; mt < 2; ++mt)
#pragma unroll
        for (int nt = 0; nt < 4; ++nt) {
            f32x4 z = {0.f, 0.f, 0.f, 0.f};
            acc[mt][nt] = z;
        }

#pragma unroll
    for (int ks = 0; ks < 4; ++ks) {
        bf16x8 bfr[4];
#pragma unroll
        for (int nt = 0; nt < 4; ++nt) {
            const uint4* p = (const uint4*)&Hs[(nt * 16 + ln) * 136 + ks * 32 + kq * 8];
            bfr[nt] = __builtin_bit_cast(bf16x8, *p);
        }
        bf16x8 afr[2];
#pragma unroll
        for (int mt = 0; mt < 2; ++mt) {
            int colA = w * 32 + mt * 16 + ln;
            afr[mt] = *(const bf16x8*)(Ppack + ((size_t)(ks * 4 + kq) * 128 + colA) * 8);
        }
#pragma unroll
        for (int mt = 0; mt < 2; ++mt)
#pragma unroll
            for (int nt = 0; nt < 4; ++nt)
                acc[mt][nt] = __builtin_amdgcn_mfma_f32_16x16x32_bf16(
                    afr[mt], bfr[nt], acc[mt][nt], 0, 0, 0);
    }

#pragma unroll
    for (int mt = 0; mt < 2; ++mt) {
        int col = w * 32 + mt * 16 + kq * 4;
        float4 bb = *(const float4*)(bp + col);
#pragma unroll
        for (int nt = 0; nt < 4; ++nt) {
            int node = row0 + nt * 16 + ln;
            if (node < M) {
                float4 o;
                o.x = fmaxf(acc[mt][nt][0] + bb.x, 0.f);
                o.y = fmaxf(acc[mt][nt][1] + bb.y, 0.f);
                o.z = fmaxf(acc[mt][nt][2] + bb.z, 0.f);
                o.w = fmaxf(acc[mt][nt][3] + bb.w, 0.f);
                *(float4*)(C + (size_t)node * 128 + col) = o;
            }
        }
    }
}

// ---------------------------------------------------------------------------
// order-preserving float<->uint mapping (0 == "-inf" sentinel)
// ---------------------------------------------------------------------------
__device__ inline unsigned ford(float f) {
    int b = __float_as_int(f);
    return (b >= 0) ? ((unsigned)b | 0x80000000u) : (unsigned)(~b);
}
__device__ inline float fdec(unsigned u) {
    int b = (u & 0x80000000u) ? (int)(u & 0x7FFFFFFFu) : ~((int)u);
    return __int_as_float(b);
}

// ---------------------------------------------------------------------------
// score: per (edge, head): sum_d lrelu(fs[src]+fd[dst]) * attn ; segment max
// ---------------------------------------------------------------------------
__global__ __launch_bounds__(256) void score_kernel(
    const unsigned short* __restrict__ fs, const unsigned short* __restrict__ fd,
    const float* __restrict__ attn, const int* __restrict__ src,
    const int* __restrict__ dst, float* __restrict__ score,
    unsigned* __restrict__ smax)
{
    int e = blockIdx.x * 4 + (threadIdx.x >> 6);
    if (e >= NEDGE) return;
    int l = threadIdx.x & 63;
    int s = src[e];
    int d = dst[e];
    int o = l * 8;

    uint4 a = *(const uint4*)(fs + (size_t)s * 512 + o);
    uint4 b = *(const uint4*)(fd + (size_t)d * 512 + o);
    float4 w0 = *(const float4*)(attn + o);
    float4 w1 = *(const float4*)(attn + o + 4);

    float p = 0.f;
    p = fmaf(lrelu(blo(a.x) + blo(b.x)), w0.x, p);
    p = fmaf(lrelu(bhi(a.x) + bhi(b.x)), w0.y, p);
    p = fmaf(lrelu(blo(a.y) + blo(b.y)), w0.z, p);
    p = fmaf(lrelu(bhi(a.y) + bhi(b.y)), w0.w, p);
    p = fmaf(lrelu(blo(a.z) + blo(b.z)), w1.x, p);
    p = fmaf(lrelu(bhi(a.z) + bhi(b.z)), w1.y, p);
    p = fmaf(lrelu(blo(a.w) + blo(b.w)), w1.z, p);
    p = fmaf(lrelu(bhi(a.w) + bhi(b.w)), w1.w, p);

#pragma unroll
    for (int m = 1; m < 16; m <<= 1)
        p += __shfl_xor(p, m, 64);

    if ((l & 15) == 0) {
        int h = l >> 4;
        score[e * 4 + h] = p;
        atomicMax(&smax[d * 4 + h], ford(p));
    }
}

__global__ __launch_bounds__(256) void softmax_kernel(
    const int* __restrict__ dst, float* __restrict__ score_ex,
    const unsigned* __restrict__ smax, float* __restrict__ denom)
{
    int t = blockIdx.x * 256 + threadIdx.x;
    if (t >= NEDGE * 4) return;
    int e = t >> 2, h = t & 3;
    int d = dst[e];
    float m = fdec(smax[d * 4 + h]);
    float ex = __expf(score_ex[t] - m);
    score_ex[t] = ex;
    atomicAdd(&denom[d * 4 + h], ex);
}

__global__ __launch_bounds__(256) void aggregate_kernel(
    const unsigned short* __restrict__ fs, const float* __restrict__ ex,
    const float* __restrict__ denom, const int* __restrict__ src,
    const int* __restrict__ dst, float* __restrict__ edge_out)
{
    int e = blockIdx.x * 4 + (threadIdx.x >> 6);
    if (e >= NEDGE) return;
    int l = threadIdx.x & 63;
    int s = src[e];
    int d = dst[e];

    float alpha[4];
#pragma unroll
    for (int h = 0; h < 4; ++h)
        alpha[h] = ex[e * 4 + h] / denom[d * 4 + h] * 0.25f;

    int o = l * 2;
    float v0 = 0.f, v1 = 0.f;
#pragma unroll
    for (int h = 0; h < 4; ++h) {
        unsigned w = *(const unsigned*)(fs + (size_t)s * 512 + h * 128 + o);
        v0 = fmaf(alpha[h], blo(w), v0);
        v1 = fmaf(alpha[h], bhi(w), v1);
    }
    atomicAdd(&edge_out[(size_t)d * 128 + o], v0);
    atomicAdd(&edge_out[(size_t)d * 128 + o + 1], v1);
}

// ---------------------------------------------------------------------------
extern "C" void kernel_launch(void* const* d_in, const int* in_sizes, int n_in,
                              void* d_out, int out_size, void* d_ws, size_t ws_size,
                              hipStream_t stream)
{
    const float* v_feat = (const float*)d_in[0];
    const float* e_feat = (const float*)d_in[1];
    const float* Wv     = (const float*)d_in[2];
    const float* bv     = (const float*)d_in[3];
    const float* gv     = (const float*)d_in[4];
    const float* betav  = (const float*)d_in[5];
    const float* We     = (const float*)d_in[6];
    const float* be     = (const float*)d_in[7];
    const float* ge     = (const float*)d_in[8];
    const float* betae  = (const float*)d_in[9];
    const float* Wsrc   = (const float*)d_in[10];
    const float* bsrc   = (const float*)d_in[11];
    const float* Wdst   = (const float*)d_in[12];
    const float* bdst   = (const float*)d_in[13];
    const float* attn   = (const float*)d_in[14];
    const float* Wp     = (const float*)d_in[15];
    const float* bp     = (const float*)d_in[16];
    const int*   src    = (const int*)d_in[17];
    const int*   dst    = (const int*)d_in[18];
    float* out = (float*)d_out;

    // workspace: fs 102.4M | fd 102.4M | ex 4M | smax 1.6M | denom 1.6M |
    //            packs (128K + 128K + 32K)  ~= 212 MB
    unsigned short* fs = (unsigned short*)d_ws;
    unsigned short* fd = fs + (size_t)NV * 512;
    float* exb   = (float*)(fd + (size_t)NE_N * 512);
    unsigned* smax = (unsigned*)(exb + (size_t)NEDGE * 4);
    float* denom = (float*)(smax + (size_t)NE_N * 4);
    bf16_t* pS = (bf16_t*)(denom + (size_t)NE_N * 4);
    bf16_t* pD = pS + 65536;
    bf16_t* pP = pD + 65536;

    prep_kernel<<<72, 256, 0, stream>>>(Wsrc, Wdst, Wp, pS, pD, pP);

    enc_proj_kernel<<<1563, 256, 0, stream>>>(v_feat, Wv, bv, gv, betav,
                                              pS, bsrc, fs, NV);
    enc_proj_kernel<<<1563, 256, 0, stream>>>(e_feat, We, be, ge, betae,
                                              pD, bdst, fd, NE_N);

    hipMemsetAsync(smax, 0, (size_t)NE_N * 4 * sizeof(unsigned), stream);
    hipMemsetAsync(denom, 0, (size_t)NE_N * 4 * sizeof(float), stream);
    hipMemsetAsync(out, 0, (size_t)NE_N * 128 * sizeof(float), stream);

    score_kernel<<<NEDGE / 4, 256, 0, stream>>>(fs, fd, attn, src, dst, exb, smax);
    softmax_kernel<<<(NEDGE * 4 + 255) / 256, 256, 0, stream>>>(dst, exb, smax, denom);
    aggregate_kernel<<<NEDGE / 4, 256, 0, stream>>>(fs, exb, denom, src, dst, out);

    final_gemm_kernel<<<1563, 256, 0, stream>>>(out, pP, bp, out, NE_N);
}

// Round 4
// 668.550 us; speedup vs baseline: 1.3110x; 1.1592x over previous
//
#include <hip/hip_runtime.h>
#include <hip/hip_bf16.h>
#include <math.h>

#define NV 100000
#define NE_N 100000
#define NEDGE 250000
#define NEG 0.2f
#define LN_EPS 1e-5f

typedef __bf16 bf16_t;
typedef __bf16 bf16x8 __attribute__((ext_vector_type(8)));
typedef float f32x4 __attribute__((ext_vector_type(4)));

__device__ inline unsigned short f2bfu(float f) {
    return __builtin_bit_cast(unsigned short, (__bf16)f);
}
__device__ inline float bfu2f(unsigned short u) {
    return (float)__builtin_bit_cast(__bf16, u);
}
__device__ inline float blo(unsigned w) { return __uint_as_float(w << 16); }
__device__ inline float bhi(unsigned w) { return __uint_as_float(w & 0xffff0000u); }
__device__ inline float lrelu(float x) { return x > 0.f ? x : NEG * x; }

// ---------------------------------------------------------------------------
// prep: pack W matrices into bf16 A-fragment order:
//   pack[((ksq)*N + col)*8 + j] = W[ksq*8 + j][col],  ksq = 0..15 (K=128)
// ---------------------------------------------------------------------------
__global__ __launch_bounds__(256) void prep_kernel(
    const float* __restrict__ Wsrc, const float* __restrict__ Wdst,
    const float* __restrict__ Wp, bf16_t* __restrict__ pS,
    bf16_t* __restrict__ pD, bf16_t* __restrict__ pP)
{
    int t = blockIdx.x * 256 + threadIdx.x;
    if (t < 8192) {
        int ksq = t >> 9, col = t & 511;
#pragma unroll
        for (int j = 0; j < 8; ++j)
            pS[(size_t)t * 8 + j] = (bf16_t)Wsrc[(ksq * 8 + j) * 512 + col];
    } else if (t < 16384) {
        int g = t - 8192;
        int ksq = g >> 9, col = g & 511;
#pragma unroll
        for (int j = 0; j < 8; ++j)
            pD[(size_t)g * 8 + j] = (bf16_t)Wdst[(ksq * 8 + j) * 512 + col];
    } else if (t < 18432) {
        int g = t - 16384;
        int ksq = g >> 7, col = g & 127;
#pragma unroll
        for (int j = 0; j < 8; ++j)
            pP[(size_t)g * 8 + j] = (bf16_t)Wp[(ksq * 8 + j) * 128 + col];
    }
}

// ---------------------------------------------------------------------------
// CSR build kernels
// ---------------------------------------------------------------------------
__global__ __launch_bounds__(256) void count_kernel(
    const int* __restrict__ dst, int* __restrict__ deg)
{
    int t = blockIdx.x * 256 + threadIdx.x;
    if (t < NEDGE) atomicAdd(&deg[dst[t]], 1);
}

__global__ __launch_bounds__(256) void scan1_kernel(
    const int* __restrict__ deg, int* __restrict__ offs, int* __restrict__ bsum)
{
    __shared__ int s[256];
    int i = blockIdx.x * 256 + threadIdx.x;
    int v = (i < NE_N) ? deg[i] : 0;
    s[threadIdx.x] = v;
    __syncthreads();
    for (int off = 1; off < 256; off <<= 1) {
        int t_ = (threadIdx.x >= off) ? s[threadIdx.x - off] : 0;
        __syncthreads();
        s[threadIdx.x] += t_;
        __syncthreads();
    }
    if (i < NE_N) offs[i] = s[threadIdx.x] - v;   // exclusive within block
    if (threadIdx.x == 255) bsum[blockIdx.x] = s[255];
}

__global__ __launch_bounds__(512) void scan2_kernel(int* __restrict__ bsum, int nb)
{
    __shared__ int s[512];
    int t = threadIdx.x;
    int v = (t < nb) ? bsum[t] : 0;
    s[t] = v;
    __syncthreads();
    for (int off = 1; off < 512; off <<= 1) {
        int t_ = (t >= off) ? s[t - off] : 0;
        __syncthreads();
        s[t] += t_;
        __syncthreads();
    }
    if (t < nb) bsum[t] = s[t] - v;               // exclusive
}

__global__ __launch_bounds__(256) void scan3_kernel(
    int* __restrict__ offs, const int* __restrict__ bsum, int* __restrict__ cursor)
{
    int i = blockIdx.x * 256 + threadIdx.x;
    if (i < NE_N) {
        int o = offs[i] + bsum[blockIdx.x];
        offs[i] = o;
        cursor[i] = o;
    }
}

__global__ __launch_bounds__(256) void scatter_kernel(
    const int* __restrict__ dst, int* __restrict__ cursor, int* __restrict__ eidx)
{
    int t = blockIdx.x * 256 + threadIdx.x;
    if (t < NEDGE) {
        int pos = atomicAdd(&cursor[dst[t]], 1);
        eidx[pos] = t;
    }
}

// ---------------------------------------------------------------------------
// Fused encoder + MFMA projection (unchanged from round 3)
// ---------------------------------------------------------------------------
__global__ __launch_bounds__(256) void enc_proj_kernel(
    const float* __restrict__ feat,
    const float* __restrict__ Wenc, const float* __restrict__ benc,
    const float* __restrict__ g, const float* __restrict__ beta,
    const bf16_t* __restrict__ Apack, const float* __restrict__ bproj,
    unsigned short* __restrict__ out, int M)
{
    __shared__ unsigned short Hs[64 * 136];
    __shared__ float red_s[256], red_q[256];
    __shared__ float s_mu[64], s_inv[64];

    int t = threadIdx.x;
    int lane = t & 63;
    int w = t >> 6;
    int row0 = blockIdx.x * 64;

    int colE = (w & 1) * 64 + lane;
    float wcol[16];
#pragma unroll
    for (int k = 0; k < 16; ++k) wcol[k] = Wenc[k * 128 + colE];
    float bcol = benc[colE];
    int rof = __builtin_amdgcn_readfirstlane(t >> 7);

    float vals[32];
#pragma unroll
    for (int i = 0; i < 32; ++i) {
        int r = 2 * i + rof;
        int grow = row0 + r;
        if (grow >= M) grow = M - 1;
        const float* fr = feat + (size_t)grow * 16;
        float acc = bcol;
#pragma unroll
        for (int k = 0; k < 16; ++k)
            acc = fmaf(fr[k], wcol[k], acc);
        acc = fmaxf(acc, 0.f);
        vals[i] = acc;
        Hs[r * 136 + colE] = f2bfu(acc);
    }
    __syncthreads();

    {
        int r = t >> 2, q = t & 3;
        float s = 0.f, s2 = 0.f;
#pragma unroll
        for (int c = q * 32; c < q * 32 + 32; ++c) {
            float v = bfu2f(Hs[r * 136 + c]);
            s += v;
            s2 = fmaf(v, v, s2);
        }
        red_s[t] = s;
        red_q[t] = s2;
    }
    __syncthreads();
    if (t < 64) {
        float s  = red_s[t * 4] + red_s[t * 4 + 1] + red_s[t * 4 + 2] + red_s[t * 4 + 3];
        float s2 = red_q[t * 4] + red_q[t * 4 + 1] + red_q[t * 4 + 2] + red_q[t * 4 + 3];
        float mu = s * (1.f / 128.f);
        float var = s2 * (1.f / 128.f) - mu * mu;
        s_mu[t] = mu;
        s_inv[t] = rsqrtf(var + LN_EPS);
    }
    __syncthreads();

    {
        float gc = g[colE], bc = beta[colE];
#pragma unroll
        for (int i = 0; i < 32; ++i) {
            int r = 2 * i + rof;
            float nv = (vals[i] - s_mu[r]) * s_inv[r] * gc + bc;
            Hs[r * 136 + colE] = f2bfu(nv);
        }
    }
    __syncthreads();

    int kq = lane >> 4;
    int ln = lane & 15;
    int wcol0 = w * 128;

    f32x4 acc[8][4];
#pragma unroll
    for (int mt = 0; mt < 8; ++mt)
#pragma unroll
        for (int nt = 0; nt < 4; ++nt) {
            f32x4 z = {0.f, 0.f, 0.f, 0.f};
            acc[mt][nt] = z;
        }

#pragma unroll
    for (int ks = 0; ks < 4; ++ks) {
        bf16x8 bfr[4];
#pragma unroll
        for (int nt = 0; nt < 4; ++nt) {
            const uint4* p = (const uint4*)&Hs[(nt * 16 + ln) * 136 + ks * 32 + kq * 8];
            bfr[nt] = __builtin_bit_cast(bf16x8, *p);
        }
        bf16x8 afr[8];
#pragma unroll
        for (int mt = 0; mt < 8; ++mt) {
            int colA = wcol0 + mt * 16 + ln;
            afr[mt] = *(const bf16x8*)(Apack + ((size_t)(ks * 4 + kq) * 512 + colA) * 8);
        }
#pragma unroll
        for (int mt = 0; mt < 8; ++mt)
#pragma unroll
            for (int nt = 0; nt < 4; ++nt)
                acc[mt][nt] = __builtin_amdgcn_mfma_f32_16x16x32_bf16(
                    afr[mt], bfr[nt], acc[mt][nt], 0, 0, 0);
    }

#pragma unroll
    for (int mt = 0; mt < 8; ++mt) {
        int col = wcol0 + mt * 16 + kq * 4;
        float4 bb = *(const float4*)(bproj + col);
#pragma unroll
        for (int nt = 0; nt < 4; ++nt) {
            int node = row0 + nt * 16 + ln;
            if (node < M) {
                ushort4 o;
                o.x = f2bfu(acc[mt][nt][0] + bb.x);
                o.y = f2bfu(acc[mt][nt][1] + bb.y);
                o.z = f2bfu(acc[mt][nt][2] + bb.z);
                o.w = f2bfu(acc[mt][nt][3] + bb.w);
                *(ushort4*)(out + (size_t)node * 512 + col) = o;
            }
        }
    }
}

// ---------------------------------------------------------------------------
// final GEMM (MFMA): C[M,128] = relu(A[M,128] @ Wp + bp), in place (A == C)
// ---------------------------------------------------------------------------
__global__ __launch_bounds__(256) void final_gemm_kernel(
    const float* __restrict__ A, const bf16_t* __restrict__ Ppack,
    const float* __restrict__ bp, float* __restrict__ C, int M)
{
    __shared__ unsigned short Hs[64 * 136];
    int t = threadIdx.x;
    int lane = t & 63;
    int w = t >> 6;
    int row0 = blockIdx.x * 64;

#pragma unroll
    for (int i = 0; i < 8; ++i) {
        int f4 = i * 256 + t;
        int r = f4 >> 5;
        int c4 = (f4 & 31) * 4;
        float4 v = make_float4(0.f, 0.f, 0.f, 0.f);
        if (row0 + r < M)
            v = ((const float4*)(A + (size_t)(row0 + r) * 128))[f4 & 31];
        ushort4 o;
        o.x = f2bfu(v.x); o.y = f2bfu(v.y); o.z = f2bfu(v.z); o.w = f2bfu(v.w);
        *(ushort4*)&Hs[r * 136 + c4] = o;
    }
    __syncthreads();

    int kq = lane >> 4;
    int ln = lane & 15;

    f32x4 acc[2][4];
#pragma unroll
    for (int mt = 0; mt < 2; ++mt)
#pragma unroll
        for (int nt = 0; nt < 4; ++nt) {
            f32x4 z = {0.f, 0.f, 0.f, 0.f};
            acc[mt][nt] = z;
        }

#pragma unroll
    for (int ks = 0; ks < 4; ++ks) {
        bf16x8 bfr[4];
#pragma unroll
        for (int nt = 0; nt < 4; ++nt) {
            const uint4* p = (const uint4*)&Hs[(nt * 16 + ln) * 136 + ks * 32 + kq * 8];
            bfr[nt] = __builtin_bit_cast(bf16x8, *p);
        }
        bf16x8 afr[2];
#pragma unroll
        for (int mt = 0; mt < 2; ++mt) {
            int colA = w * 32 + mt * 16 + ln;
            afr[mt] = *(const bf16x8*)(Ppack + ((size_t)(ks * 4 + kq) * 128 + colA) * 8);
        }
#pragma unroll
        for (int mt = 0; mt < 2; ++mt)
#pragma unroll
            for (int nt = 0; nt < 4; ++nt)
                acc[mt][nt] = __builtin_amdgcn_mfma_f32_16x16x32_bf16(
                    afr[mt], bfr[nt], acc[mt][nt], 0, 0, 0);
    }

#pragma unroll
    for (int mt = 0; mt < 2; ++mt) {
        int col = w * 32 + mt * 16 + kq * 4;
        float4 bb = *(const float4*)(bp + col);
#pragma unroll
        for (int nt = 0; nt < 4; ++nt) {
            int node = row0 + nt * 16 + ln;
            if (node < M) {
                float4 o;
                o.x = fmaxf(acc[mt][nt][0] + bb.x, 0.f);
                o.y = fmaxf(acc[mt][nt][1] + bb.y, 0.f);
                o.z = fmaxf(acc[mt][nt][2] + bb.z, 0.f);
                o.w = fmaxf(acc[mt][nt][3] + bb.w, 0.f);
                *(float4*)(C + (size_t)node * 128 + col) = o;
            }
        }
    }
}

// ---------------------------------------------------------------------------
// score: per (edge, head): sum_d lrelu(fs[src]+fd[dst]) * attn
// one wave per edge; lane owns 8 contiguous bf16 elements (16 lanes per head)
// ---------------------------------------------------------------------------
__global__ __launch_bounds__(256) void score_kernel(
    const unsigned short* __restrict__ fs, const unsigned short* __restrict__ fd,
    const float* __restrict__ attn, const int* __restrict__ src,
    const int* __restrict__ dst, float* __restrict__ score)
{
    int e = blockIdx.x * 4 + (threadIdx.x >> 6);
    if (e >= NEDGE) return;
    int l = threadIdx.x & 63;
    int s = src[e];
    int d = dst[e];
    int o = l * 8;

    uint4 a = *(const uint4*)(fs + (size_t)s * 512 + o);
    uint4 b = *(const uint4*)(fd + (size_t)d * 512 + o);
    float4 w0 = *(const float4*)(attn + o);
    float4 w1 = *(const float4*)(attn + o + 4);

    float p = 0.f;
    p = fmaf(lrelu(blo(a.x) + blo(b.x)), w0.x, p);
    p = fmaf(lrelu(bhi(a.x) + bhi(b.x)), w0.y, p);
    p = fmaf(lrelu(blo(a.y) + blo(b.y)), w0.z, p);
    p = fmaf(lrelu(bhi(a.y) + bhi(b.y)), w0.w, p);
    p = fmaf(lrelu(blo(a.z) + blo(b.z)), w1.x, p);
    p = fmaf(lrelu(bhi(a.z) + bhi(b.z)), w1.y, p);
    p = fmaf(lrelu(blo(a.w) + blo(b.w)), w1.z, p);
    p = fmaf(lrelu(bhi(a.w) + bhi(b.w)), w1.w, p);

#pragma unroll
    for (int m = 1; m < 16; m <<= 1)
        p += __shfl_xor(p, m, 64);

    if ((l & 15) == 0)
        score[e * 4 + (l >> 4)] = p;
}

// ---------------------------------------------------------------------------
// fused segment softmax + aggregate, dst-centric, no atomics.
// one wave per dst node: max/sum over its edges (broadcast score loads),
// then gather fs[src] rows, fold heads, write one coalesced row.
// ---------------------------------------------------------------------------
__global__ __launch_bounds__(256) void softagg_kernel(
    const unsigned short* __restrict__ fs, const float* __restrict__ score,
    const int* __restrict__ src, const int* __restrict__ offs,
    const int* __restrict__ deg, const int* __restrict__ eidx,
    float* __restrict__ out)
{
    int d = blockIdx.x * 4 + (threadIdx.x >> 6);
    if (d >= NE_N) return;
    int l = threadIdx.x & 63;
    int r0 = offs[d];
    int n = deg[d];

    float mx0 = -1e30f, mx1 = -1e30f, mx2 = -1e30f, mx3 = -1e30f;
    for (int i = 0; i < n; ++i) {
        float4 sc = *(const float4*)(score + (size_t)eidx[r0 + i] * 4);
        mx0 = fmaxf(mx0, sc.x); mx1 = fmaxf(mx1, sc.y);
        mx2 = fmaxf(mx2, sc.z); mx3 = fmaxf(mx3, sc.w);
    }
    float sm0 = 0.f, sm1 = 0.f, sm2 = 0.f, sm3 = 0.f;
    for (int i = 0; i < n; ++i) {
        float4 sc = *(const float4*)(score + (size_t)eidx[r0 + i] * 4);
        sm0 += __expf(sc.x - mx0); sm1 += __expf(sc.y - mx1);
        sm2 += __expf(sc.z - mx2); sm3 += __expf(sc.w - mx3);
    }
    float inv0 = 0.25f / sm0, inv1 = 0.25f / sm1;
    float inv2 = 0.25f / sm2, inv3 = 0.25f / sm3;

    int o = l * 2;
    float v0 = 0.f, v1 = 0.f;
    for (int i = 0; i < n; ++i) {
        int eid = eidx[r0 + i];
        int s = src[eid];
        float4 sc = *(const float4*)(score + (size_t)eid * 4);
        float a0 = __expf(sc.x - mx0) * inv0;
        float a1 = __expf(sc.y - mx1) * inv1;
        float a2 = __expf(sc.z - mx2) * inv2;
        float a3 = __expf(sc.w - mx3) * inv3;
        const unsigned short* fr = fs + (size_t)s * 512 + o;
        unsigned w0 = *(const unsigned*)(fr);
        unsigned w1 = *(const unsigned*)(fr + 128);
        unsigned w2 = *(const unsigned*)(fr + 256);
        unsigned w3 = *(const unsigned*)(fr + 384);
        v0 = fmaf(a0, blo(w0), v0); v1 = fmaf(a0, bhi(w0), v1);
        v0 = fmaf(a1, blo(w1), v0); v1 = fmaf(a1, bhi(w1), v1);
        v0 = fmaf(a2, blo(w2), v0); v1 = fmaf(a2, bhi(w2), v1);
        v0 = fmaf(a3, blo(w3), v0); v1 = fmaf(a3, bhi(w3), v1);
    }
    *(float2*)(out + (size_t)d * 128 + o) = make_float2(v0, v1);
}

// ---------------------------------------------------------------------------
extern "C" void kernel_launch(void* const* d_in, const int* in_sizes, int n_in,
                              void* d_out, int out_size, void* d_ws, size_t ws_size,
                              hipStream_t stream)
{
    const float* v_feat = (const float*)d_in[0];
    const float* e_feat = (const float*)d_in[1];
    const float* Wv     = (const float*)d_in[2];
    const float* bv     = (const float*)d_in[3];
    const float* gv     = (const float*)d_in[4];
    const float* betav  = (const float*)d_in[5];
    const float* We     = (const float*)d_in[6];
    const float* be     = (const float*)d_in[7];
    const float* ge     = (const float*)d_in[8];
    const float* betae  = (const float*)d_in[9];
    const float* Wsrc   = (const float*)d_in[10];
    const float* bsrc   = (const float*)d_in[11];
    const float* Wdst   = (const float*)d_in[12];
    const float* bdst   = (const float*)d_in[13];
    const float* attn   = (const float*)d_in[14];
    const float* Wp     = (const float*)d_in[15];
    const float* bp     = (const float*)d_in[16];
    const int*   src    = (const int*)d_in[17];
    const int*   dst    = (const int*)d_in[18];
    float* out = (float*)d_out;

    // workspace: fs 102.4M | fd 102.4M | ex 4M | deg/offs/cursor 1.2M |
    //            bsum 2K | eidx 1M | packs ~300K  => ~211.3 MB
    unsigned short* fs = (unsigned short*)d_ws;
    unsigned short* fd = fs + (size_t)NV * 512;
    float* exb  = (float*)(fd + (size_t)NE_N * 512);
    int* deg    = (int*)(exb + (size_t)NEDGE * 4);
    int* offs   = deg + NE_N;
    int* cursor = offs + NE_N;
    int* bsum   = cursor + NE_N;
    int* eidx   = bsum + 512;
    bf16_t* pS  = (bf16_t*)(eidx + NEDGE);
    bf16_t* pD  = pS + 65536;
    bf16_t* pP  = pD + 65536;

    const int NB_SCAN = (NE_N + 255) / 256;   // 391

    prep_kernel<<<72, 256, 0, stream>>>(Wsrc, Wdst, Wp, pS, pD, pP);

    // CSR build
    hipMemsetAsync(deg, 0, (size_t)NE_N * sizeof(int), stream);
    count_kernel<<<(NEDGE + 255) / 256, 256, 0, stream>>>(dst, deg);
    scan1_kernel<<<NB_SCAN, 256, 0, stream>>>(deg, offs, bsum);
    scan2_kernel<<<1, 512, 0, stream>>>(bsum, NB_SCAN);
    scan3_kernel<<<NB_SCAN, 256, 0, stream>>>(offs, bsum, cursor);
    scatter_kernel<<<(NEDGE + 255) / 256, 256, 0, stream>>>(dst, cursor, eidx);

    enc_proj_kernel<<<1563, 256, 0, stream>>>(v_feat, Wv, bv, gv, betav,
                                              pS, bsrc, fs, NV);
    enc_proj_kernel<<<1563, 256, 0, stream>>>(e_feat, We, be, ge, betae,
                                              pD, bdst, fd, NE_N);

    score_kernel<<<NEDGE / 4, 256, 0, stream>>>(fs, fd, attn, src, dst, exb);
    softagg_kernel<<<NE_N / 4, 256, 0, stream>>>(fs, exb, src, offs, deg, eidx, out);

    final_gemm_kernel<<<1563, 256, 0, stream>>>(out, pP, bp, out, NE_N);
}

// Round 5
// 504.951 us; speedup vs baseline: 1.7358x; 1.3240x over previous
//
#include <hip/hip_runtime.h>
#include <hip/hip_bf16.h>
#include <math.h>

#define NV 100000
#define NE_N 100000
#define NEDGE 250000
#define NEG 0.2f
#define LN_EPS 1e-5f

typedef __bf16 bf16_t;
typedef __bf16 bf16x8 __attribute__((ext_vector_type(8)));
typedef float f32x4 __attribute__((ext_vector_type(4)));

__device__ inline unsigned short f2bfu(float f) {
    return __builtin_bit_cast(unsigned short, (__bf16)f);
}
__device__ inline float bfu2f(unsigned short u) {
    return (float)__builtin_bit_cast(__bf16, u);
}
__device__ inline float blo(unsigned w) { return __uint_as_float(w << 16); }
__device__ inline float bhi(unsigned w) { return __uint_as_float(w & 0xffff0000u); }
__device__ inline float lrelu(float x) { return x > 0.f ? x : NEG * x; }

// ---------------------------------------------------------------------------
// prep: pack W matrices into bf16 A-fragment order:
//   pack[((ksq)*N + col)*8 + j] = W[ksq*8 + j][col],  ksq = 0..15 (K=128)
// ---------------------------------------------------------------------------
__global__ __launch_bounds__(256) void prep_kernel(
    const float* __restrict__ Wsrc, const float* __restrict__ Wdst,
    const float* __restrict__ Wp, bf16_t* __restrict__ pS,
    bf16_t* __restrict__ pD, bf16_t* __restrict__ pP)
{
    int t = blockIdx.x * 256 + threadIdx.x;
    if (t < 8192) {
        int ksq = t >> 9, col = t & 511;
#pragma unroll
        for (int j = 0; j < 8; ++j)
            pS[(size_t)t * 8 + j] = (bf16_t)Wsrc[(ksq * 8 + j) * 512 + col];
    } else if (t < 16384) {
        int g = t - 8192;
        int ksq = g >> 9, col = g & 511;
#pragma unroll
        for (int j = 0; j < 8; ++j)
            pD[(size_t)g * 8 + j] = (bf16_t)Wdst[(ksq * 8 + j) * 512 + col];
    } else if (t < 18432) {
        int g = t - 16384;
        int ksq = g >> 7, col = g & 127;
#pragma unroll
        for (int j = 0; j < 8; ++j)
            pP[(size_t)g * 8 + j] = (bf16_t)Wp[(ksq * 8 + j) * 128 + col];
    }
}

// ---------------------------------------------------------------------------
// CSR build kernels
// ---------------------------------------------------------------------------
__global__ __launch_bounds__(256) void count_kernel(
    const int* __restrict__ dst, int* __restrict__ deg)
{
    int t = blockIdx.x * 256 + threadIdx.x;
    if (t < NEDGE) atomicAdd(&deg[dst[t]], 1);
}

__global__ __launch_bounds__(256) void scan1_kernel(
    const int* __restrict__ deg, int* __restrict__ offs, int* __restrict__ bsum)
{
    __shared__ int s[256];
    int i = blockIdx.x * 256 + threadIdx.x;
    int v = (i < NE_N) ? deg[i] : 0;
    s[threadIdx.x] = v;
    __syncthreads();
    for (int off = 1; off < 256; off <<= 1) {
        int t_ = (threadIdx.x >= off) ? s[threadIdx.x - off] : 0;
        __syncthreads();
        s[threadIdx.x] += t_;
        __syncthreads();
    }
    if (i < NE_N) offs[i] = s[threadIdx.x] - v;   // exclusive within block
    if (threadIdx.x == 255) bsum[blockIdx.x] = s[255];
}

__global__ __launch_bounds__(512) void scan2_kernel(int* __restrict__ bsum, int nb)
{
    __shared__ int s[512];
    int t = threadIdx.x;
    int v = (t < nb) ? bsum[t] : 0;
    s[t] = v;
    __syncthreads();
    for (int off = 1; off < 512; off <<= 1) {
        int t_ = (t >= off) ? s[t - off] : 0;
        __syncthreads();
        s[t] += t_;
        __syncthreads();
    }
    if (t < nb) bsum[t] = s[t] - v;               // exclusive
}

__global__ __launch_bounds__(256) void scan3_kernel(
    int* __restrict__ offs, const int* __restrict__ bsum, int* __restrict__ cursor)
{
    int i = blockIdx.x * 256 + threadIdx.x;
    if (i < NE_N) {
        int o = offs[i] + bsum[blockIdx.x];
        offs[i] = o;
        cursor[i] = o;
    }
}

__global__ __launch_bounds__(256) void scatter_kernel(
    const int* __restrict__ dst, int* __restrict__ cursor, int* __restrict__ eidx)
{
    int t = blockIdx.x * 256 + threadIdx.x;
    if (t < NEDGE) {
        int pos = atomicAdd(&cursor[dst[t]], 1);
        eidx[pos] = t;
    }
}

// ---------------------------------------------------------------------------
// Fused encoder + MFMA projection.
// Register-pressure restructured: B-frags (h tile) persistent (64 VGPRs),
// one m-tile of accumulators live at a time (16 AGPRs) -> 3 waves/SIMD.
// ---------------------------------------------------------------------------
__global__ __launch_bounds__(256, 3) void enc_proj_kernel(
    const float* __restrict__ feat,
    const float* __restrict__ Wenc, const float* __restrict__ benc,
    const float* __restrict__ g, const float* __restrict__ beta,
    const bf16_t* __restrict__ Apack, const float* __restrict__ bproj,
    unsigned short* __restrict__ out, int M)
{
    __shared__ unsigned short Hs[64 * 136];
    __shared__ float red_s[256], red_q[256];
    __shared__ float s_mu[64], s_inv[64];

    int t = threadIdx.x;
    int lane = t & 63;
    int w = t >> 6;
    int row0 = blockIdx.x * 64;

    int colE = (w & 1) * 64 + lane;
    float wcol[16];
#pragma unroll
    for (int k = 0; k < 16; ++k) wcol[k] = Wenc[k * 128 + colE];
    float bcol = benc[colE];
    int rof = __builtin_amdgcn_readfirstlane(t >> 7);

#pragma unroll
    for (int i = 0; i < 32; ++i) {
        int r = 2 * i + rof;
        int grow = row0 + r;
        if (grow >= M) grow = M - 1;
        const float* fr = feat + (size_t)grow * 16;
        float acc = bcol;
#pragma unroll
        for (int k = 0; k < 16; ++k)
            acc = fmaf(fr[k], wcol[k], acc);
        Hs[r * 136 + colE] = f2bfu(fmaxf(acc, 0.f));
    }
    __syncthreads();

    {
        int r = t >> 2, q = t & 3;
        float s = 0.f, s2 = 0.f;
#pragma unroll
        for (int c = q * 32; c < q * 32 + 32; ++c) {
            float v = bfu2f(Hs[r * 136 + c]);
            s += v;
            s2 = fmaf(v, v, s2);
        }
        red_s[t] = s;
        red_q[t] = s2;
    }
    __syncthreads();
    if (t < 64) {
        float s  = red_s[t * 4] + red_s[t * 4 + 1] + red_s[t * 4 + 2] + red_s[t * 4 + 3];
        float s2 = red_q[t * 4] + red_q[t * 4 + 1] + red_q[t * 4 + 2] + red_q[t * 4 + 3];
        float mu = s * (1.f / 128.f);
        float var = s2 * (1.f / 128.f) - mu * mu;
        s_mu[t] = mu;
        s_inv[t] = rsqrtf(var + LN_EPS);
    }
    __syncthreads();

    {
        float gc = g[colE], bc = beta[colE];
#pragma unroll
        for (int i = 0; i < 32; ++i) {
            int r = 2 * i + rof;
            float v = bfu2f(Hs[r * 136 + colE]);
            Hs[r * 136 + colE] = f2bfu((v - s_mu[r]) * s_inv[r] * gc + bc);
        }
    }
    __syncthreads();

    // ---- MFMA: wave w computes 64 rows x 128 cols, one m-tile at a time
    int kq = lane >> 4;
    int ln = lane & 15;
    int wcol0 = w * 128;

    // persistent B fragments (h tile): 16 x bf16x8 = 64 VGPRs
    bf16x8 bfr[4][4];
#pragma unroll
    for (int ks = 0; ks < 4; ++ks)
#pragma unroll
        for (int nt = 0; nt < 4; ++nt) {
            const uint4* p = (const uint4*)&Hs[(nt * 16 + ln) * 136 + ks * 32 + kq * 8];
            bfr[ks][nt] = __builtin_bit_cast(bf16x8, *p);
        }

#pragma unroll
    for (int mt = 0; mt < 8; ++mt) {
        int colA = wcol0 + mt * 16 + ln;
        bf16x8 afr[4];
#pragma unroll
        for (int ks = 0; ks < 4; ++ks)
            afr[ks] = *(const bf16x8*)(Apack + ((size_t)(ks * 4 + kq) * 512 + colA) * 8);

        f32x4 acc[4];
#pragma unroll
        for (int nt = 0; nt < 4; ++nt) {
            f32x4 z = {0.f, 0.f, 0.f, 0.f};
            acc[nt] = z;
        }
#pragma unroll
        for (int ks = 0; ks < 4; ++ks)
#pragma unroll
            for (int nt = 0; nt < 4; ++nt)
                acc[nt] = __builtin_amdgcn_mfma_f32_16x16x32_bf16(
                    afr[ks], bfr[ks][nt], acc[nt], 0, 0, 0);

        int col = wcol0 + mt * 16 + kq * 4;
        float4 bb = *(const float4*)(bproj + col);
#pragma unroll
        for (int nt = 0; nt < 4; ++nt) {
            int node = row0 + nt * 16 + ln;
            if (node < M) {
                ushort4 o;
                o.x = f2bfu(acc[nt][0] + bb.x);
                o.y = f2bfu(acc[nt][1] + bb.y);
                o.z = f2bfu(acc[nt][2] + bb.z);
                o.w = f2bfu(acc[nt][3] + bb.w);
                *(ushort4*)(out + (size_t)node * 512 + col) = o;
            }
        }
    }
}

// ---------------------------------------------------------------------------
// final GEMM (MFMA): C[M,128] = relu(A[M,128] @ Wp + bp), in place (A == C)
// ---------------------------------------------------------------------------
__global__ __launch_bounds__(256) void final_gemm_kernel(
    const float* __restrict__ A, const bf16_t* __restrict__ Ppack,
    const float* __restrict__ bp, float* __restrict__ C, int M)
{
    __shared__ unsigned short Hs[64 * 136];
    int t = threadIdx.x;
    int lane = t & 63;
    int w = t >> 6;
    int row0 = blockIdx.x * 64;

#pragma unroll
    for (int i = 0; i < 8; ++i) {
        int f4 = i * 256 + t;
        int r = f4 >> 5;
        int c4 = (f4 & 31) * 4;
        float4 v = make_float4(0.f, 0.f, 0.f, 0.f);
        if (row0 + r < M)
            v = ((const float4*)(A + (size_t)(row0 + r) * 128))[f4 & 31];
        ushort4 o;
        o.x = f2bfu(v.x); o.y = f2bfu(v.y); o.z = f2bfu(v.z); o.w = f2bfu(v.w);
        *(ushort4*)&Hs[r * 136 + c4] = o;
    }
    __syncthreads();

    int kq = lane >> 4;
    int ln = lane & 15;

    f32x4 acc[2][4];
#pragma unroll
    for (int mt = 0; mt < 2; ++mt)
#pragma unroll
        for (int nt = 0; nt < 4; ++nt) {
            f32x4 z = {0.f, 0.f, 0.f, 0.f};
            acc[mt][nt] = z;
        }

#pragma unroll
    for (int ks = 0; ks < 4; ++ks) {
        bf16x8 bfr[4];
#pragma unroll
        for (int nt = 0; nt < 4; ++nt) {
            const uint4* p = (const uint4*)&Hs[(nt * 16 + ln) * 136 + ks * 32 + kq * 8];
            bfr[nt] = __builtin_bit_cast(bf16x8, *p);
        }
        bf16x8 afr[2];
#pragma unroll
        for (int mt = 0; mt < 2; ++mt) {
            int colA = w * 32 + mt * 16 + ln;
            afr[mt] = *(const bf16x8*)(Ppack + ((size_t)(ks * 4 + kq) * 128 + colA) * 8);
        }
#pragma unroll
        for (int mt = 0; mt < 2; ++mt)
#pragma unroll
            for (int nt = 0; nt < 4; ++nt)
                acc[mt][nt] = __builtin_amdgcn_mfma_f32_16x16x32_bf16(
                    afr[mt], bfr[nt], acc[mt][nt], 0, 0, 0);
    }

#pragma unroll
    for (int mt = 0; mt < 2; ++mt) {
        int col = w * 32 + mt * 16 + kq * 4;
        float4 bb = *(const float4*)(bp + col);
#pragma unroll
        for (int nt = 0; nt < 4; ++nt) {
            int node = row0 + nt * 16 + ln;
            if (node < M) {
                float4 o;
                o.x = fmaxf(acc[mt][nt][0] + bb.x, 0.f);
                o.y = fmaxf(acc[mt][nt][1] + bb.y, 0.f);
                o.z = fmaxf(acc[mt][nt][2] + bb.z, 0.f);
                o.w = fmaxf(acc[mt][nt][3] + bb.w, 0.f);
                *(float4*)(C + (size_t)node * 128 + col) = o;
            }
        }
    }
}

// ---------------------------------------------------------------------------
// score: per (edge, head): sum_d lrelu(fs[src]+fd[dst]) * attn
// ---------------------------------------------------------------------------
__global__ __launch_bounds__(256) void score_kernel(
    const unsigned short* __restrict__ fs, const unsigned short* __restrict__ fd,
    const float* __restrict__ attn, const int* __restrict__ src,
    const int* __restrict__ dst, float* __restrict__ score)
{
    int e = blockIdx.x * 4 + (threadIdx.x >> 6);
    if (e >= NEDGE) return;
    int l = threadIdx.x & 63;
    int s = src[e];
    int d = dst[e];
    int o = l * 8;

    uint4 a = *(const uint4*)(fs + (size_t)s * 512 + o);
    uint4 b = *(const uint4*)(fd + (size_t)d * 512 + o);
    float4 w0 = *(const float4*)(attn + o);
    float4 w1 = *(const float4*)(attn + o + 4);

    float p = 0.f;
    p = fmaf(lrelu(blo(a.x) + blo(b.x)), w0.x, p);
    p = fmaf(lrelu(bhi(a.x) + bhi(b.x)), w0.y, p);
    p = fmaf(lrelu(blo(a.y) + blo(b.y)), w0.z, p);
    p = fmaf(lrelu(bhi(a.y) + bhi(b.y)), w0.w, p);
    p = fmaf(lrelu(blo(a.z) + blo(b.z)), w1.x, p);
    p = fmaf(lrelu(bhi(a.z) + bhi(b.z)), w1.y, p);
    p = fmaf(lrelu(blo(a.w) + blo(b.w)), w1.z, p);
    p = fmaf(lrelu(bhi(a.w) + bhi(b.w)), w1.w, p);

#pragma unroll
    for (int m = 1; m < 16; m <<= 1)
        p += __shfl_xor(p, m, 64);

    if ((l & 15) == 0)
        score[e * 4 + (l >> 4)] = p;
}

// ---------------------------------------------------------------------------
// fused segment softmax + aggregate, dst-centric, no atomics.
// ---------------------------------------------------------------------------
__global__ __launch_bounds__(256) void softagg_kernel(
    const unsigned short* __restrict__ fs, const float* __restrict__ score,
    const int* __restrict__ src, const int* __restrict__ offs,
    const int* __restrict__ deg, const int* __restrict__ eidx,
    float* __restrict__ out)
{
    int d = blockIdx.x * 4 + (threadIdx.x >> 6);
    if (d >= NE_N) return;
    int l = threadIdx.x & 63;
    int r0 = offs[d];
    int n = deg[d];

    float mx0 = -1e30f, mx1 = -1e30f, mx2 = -1e30f, mx3 = -1e30f;
    for (int i = 0; i < n; ++i) {
        float4 sc = *(const float4*)(score + (size_t)eidx[r0 + i] * 4);
        mx0 = fmaxf(mx0, sc.x); mx1 = fmaxf(mx1, sc.y);
        mx2 = fmaxf(mx2, sc.z); mx3 = fmaxf(mx3, sc.w);
    }
    float sm0 = 0.f, sm1 = 0.f, sm2 = 0.f, sm3 = 0.f;
    for (int i = 0; i < n; ++i) {
        float4 sc = *(const float4*)(score + (size_t)eidx[r0 + i] * 4);
        sm0 += __expf(sc.x - mx0); sm1 += __expf(sc.y - mx1);
        sm2 += __expf(sc.z - mx2); sm3 += __expf(sc.w - mx3);
    }
    float inv0 = 0.25f / sm0, inv1 = 0.25f / sm1;
    float inv2 = 0.25f / sm2, inv3 = 0.25f / sm3;

    int o = l * 2;
    float v0 = 0.f, v1 = 0.f;
    for (int i = 0; i < n; ++i) {
        int eid = eidx[r0 + i];
        int s = src[eid];
        float4 sc = *(const float4*)(score + (size_t)eid * 4);
        float a0 = __expf(sc.x - mx0) * inv0;
        float a1 = __expf(sc.y - mx1) * inv1;
        float a2 = __expf(sc.z - mx2) * inv2;
        float a3 = __expf(sc.w - mx3) * inv3;
        const unsigned short* fr = fs + (size_t)s * 512 + o;
        unsigned w0 = *(const unsigned*)(fr);
        unsigned w1 = *(const unsigned*)(fr + 128);
        unsigned w2 = *(const unsigned*)(fr + 256);
        unsigned w3 = *(const unsigned*)(fr + 384);
        v0 = fmaf(a0, blo(w0), v0); v1 = fmaf(a0, bhi(w0), v1);
        v0 = fmaf(a1, blo(w1), v0); v1 = fmaf(a1, bhi(w1), v1);
        v0 = fmaf(a2, blo(w2), v0); v1 = fmaf(a2, bhi(w2), v1);
        v0 = fmaf(a3, blo(w3), v0); v1 = fmaf(a3, bhi(w3), v1);
    }
    *(float2*)(out + (size_t)d * 128 + o) = make_float2(v0, v1);
}

// ---------------------------------------------------------------------------
extern "C" void kernel_launch(void* const* d_in, const int* in_sizes, int n_in,
                              void* d_out, int out_size, void* d_ws, size_t ws_size,
                              hipStream_t stream)
{
    const float* v_feat = (const float*)d_in[0];
    const float* e_feat = (const float*)d_in[1];
    const float* Wv     = (const float*)d_in[2];
    const float* bv     = (const float*)d_in[3];
    const float* gv     = (const float*)d_in[4];
    const float* betav  = (const float*)d_in[5];
    const float* We     = (const float*)d_in[6];
    const float* be     = (const float*)d_in[7];
    const float* ge     = (const float*)d_in[8];
    const float* betae  = (const float*)d_in[9];
    const float* Wsrc   = (const float*)d_in[10];
    const float* bsrc   = (const float*)d_in[11];
    const float* Wdst   = (const float*)d_in[12];
    const float* bdst   = (const float*)d_in[13];
    const float* attn   = (const float*)d_in[14];
    const float* Wp     = (const float*)d_in[15];
    const float* bp     = (const float*)d_in[16];
    const int*   src    = (const int*)d_in[17];
    const int*   dst    = (const int*)d_in[18];
    float* out = (float*)d_out;

    unsigned short* fs = (unsigned short*)d_ws;
    unsigned short* fd = fs + (size_t)NV * 512;
    float* exb  = (float*)(fd + (size_t)NE_N * 512);
    int* deg    = (int*)(exb + (size_t)NEDGE * 4);
    int* offs   = deg + NE_N;
    int* cursor = offs + NE_N;
    int* bsum   = cursor + NE_N;
    int* eidx   = bsum + 512;
    bf16_t* pS  = (bf16_t*)(eidx + NEDGE);
    bf16_t* pD  = pS + 65536;
    bf16_t* pP  = pD + 65536;

    const int NB_SCAN = (NE_N + 255) / 256;   // 391

    prep_kernel<<<72, 256, 0, stream>>>(Wsrc, Wdst, Wp, pS, pD, pP);

    // CSR build
    hipMemsetAsync(deg, 0, (size_t)NE_N * sizeof(int), stream);
    count_kernel<<<(NEDGE + 255) / 256, 256, 0, stream>>>(dst, deg);
    scan1_kernel<<<NB_SCAN, 256, 0, stream>>>(deg, offs, bsum);
    scan2_kernel<<<1, 512, 0, stream>>>(bsum, NB_SCAN);
    scan3_kernel<<<NB_SCAN, 256, 0, stream>>>(offs, bsum, cursor);
    scatter_kernel<<<(NEDGE + 255) / 256, 256, 0, stream>>>(dst, cursor, eidx);

    enc_proj_kernel<<<1563, 256, 0, stream>>>(v_feat, Wv, bv, gv, betav,
                                              pS, bsrc, fs, NV);
    enc_proj_kernel<<<1563, 256, 0, stream>>>(e_feat, We, be, ge, betae,
                                              pD, bdst, fd, NE_N);

    score_kernel<<<NEDGE / 4, 256, 0, stream>>>(fs, fd, attn, src, dst, exb);
    softagg_kernel<<<NE_N / 4, 256, 0, stream>>>(fs, exb, src, offs, deg, eidx, out);

    final_gemm_kernel<<<1563, 256, 0, stream>>>(out, pP, bp, out, NE_N);
}

// Round 6
// 388.489 us; speedup vs baseline: 2.2561x; 1.2998x over previous
//
#include <hip/hip_runtime.h>
#include <hip/hip_bf16.h>
#include <math.h>

#define NV 100000
#define NE_N 100000
#define NEDGE 250000
#define NEG 0.2f
#define LN_EPS 1e-5f

typedef __bf16 bf16_t;
typedef __bf16 bf16x8 __attribute__((ext_vector_type(8)));
typedef float f32x4 __attribute__((ext_vector_type(4)));

__device__ inline unsigned short f2bfu(float f) {
    return __builtin_bit_cast(unsigned short, (__bf16)f);
}
__device__ inline float bfu2f(unsigned short u) {
    return (float)__builtin_bit_cast(__bf16, u);
}
__device__ inline float blo(unsigned w) { return __uint_as_float(w << 16); }
__device__ inline float bhi(unsigned w) { return __uint_as_float(w & 0xffff0000u); }
__device__ inline float lrelu(float x) { return x > 0.f ? x : NEG * x; }

// ---------------------------------------------------------------------------
// prep: pack W matrices into bf16 A-fragment order:
//   pack[((ksq)*N + col)*8 + j] = W[ksq*8 + j][col],  ksq = 0..15 (K=128)
// ---------------------------------------------------------------------------
__global__ __launch_bounds__(256) void prep_kernel(
    const float* __restrict__ Wsrc, const float* __restrict__ Wdst,
    const float* __restrict__ Wp, bf16_t* __restrict__ pS,
    bf16_t* __restrict__ pD, bf16_t* __restrict__ pP)
{
    int t = blockIdx.x * 256 + threadIdx.x;
    if (t < 8192) {
        int ksq = t >> 9, col = t & 511;
#pragma unroll
        for (int j = 0; j < 8; ++j)
            pS[(size_t)t * 8 + j] = (bf16_t)Wsrc[(ksq * 8 + j) * 512 + col];
    } else if (t < 16384) {
        int g = t - 8192;
        int ksq = g >> 9, col = g & 511;
#pragma unroll
        for (int j = 0; j < 8; ++j)
            pD[(size_t)g * 8 + j] = (bf16_t)Wdst[(ksq * 8 + j) * 512 + col];
    } else if (t < 18432) {
        int g = t - 16384;
        int ksq = g >> 7, col = g & 127;
#pragma unroll
        for (int j = 0; j < 8; ++j)
            pP[(size_t)g * 8 + j] = (bf16_t)Wp[(ksq * 8 + j) * 128 + col];
    }
}

// ---------------------------------------------------------------------------
// CSR build kernels
// ---------------------------------------------------------------------------
__global__ __launch_bounds__(256) void count_kernel(
    const int* __restrict__ dst, int* __restrict__ deg)
{
    int t = blockIdx.x * 256 + threadIdx.x;
    if (t < NEDGE) atomicAdd(&deg[dst[t]], 1);
}

__global__ __launch_bounds__(256) void scan1_kernel(
    const int* __restrict__ deg, int* __restrict__ offs, int* __restrict__ bsum)
{
    __shared__ int s[256];
    int i = blockIdx.x * 256 + threadIdx.x;
    int v = (i < NE_N) ? deg[i] : 0;
    s[threadIdx.x] = v;
    __syncthreads();
    for (int off = 1; off < 256; off <<= 1) {
        int t_ = (threadIdx.x >= off) ? s[threadIdx.x - off] : 0;
        __syncthreads();
        s[threadIdx.x] += t_;
        __syncthreads();
    }
    if (i < NE_N) offs[i] = s[threadIdx.x] - v;   // exclusive within block
    if (threadIdx.x == 255) bsum[blockIdx.x] = s[255];
}

__global__ __launch_bounds__(512) void scan2_kernel(int* __restrict__ bsum, int nb)
{
    __shared__ int s[512];
    int t = threadIdx.x;
    int v = (t < nb) ? bsum[t] : 0;
    s[t] = v;
    __syncthreads();
    for (int off = 1; off < 512; off <<= 1) {
        int t_ = (t >= off) ? s[t - off] : 0;
        __syncthreads();
        s[t] += t_;
        __syncthreads();
    }
    if (t < nb) bsum[t] = s[t] - v;               // exclusive
}

__global__ __launch_bounds__(256) void scan3_kernel(
    int* __restrict__ offs, const int* __restrict__ bsum, int* __restrict__ cursor)
{
    int i = blockIdx.x * 256 + threadIdx.x;
    if (i < NE_N) {
        int o = offs[i] + bsum[blockIdx.x];
        offs[i] = o;
        cursor[i] = o;
    }
}

__global__ __launch_bounds__(256) void scatter_kernel(
    const int* __restrict__ dst, int* __restrict__ cursor, int* __restrict__ eidx)
{
    int t = blockIdx.x * 256 + threadIdx.x;
    if (t < NEDGE) {
        int pos = atomicAdd(&cursor[dst[t]], 1);
        eidx[pos] = t;
    }
}

// ---------------------------------------------------------------------------
// Fused encoder + MFMA projection (round-5 register-lean structure)
// ---------------------------------------------------------------------------
__global__ __launch_bounds__(256, 3) void enc_proj_kernel(
    const float* __restrict__ feat,
    const float* __restrict__ Wenc, const float* __restrict__ benc,
    const float* __restrict__ g, const float* __restrict__ beta,
    const bf16_t* __restrict__ Apack, const float* __restrict__ bproj,
    unsigned short* __restrict__ out, int M)
{
    __shared__ unsigned short Hs[64 * 136];
    __shared__ float red_s[256], red_q[256];
    __shared__ float s_mu[64], s_inv[64];

    int t = threadIdx.x;
    int lane = t & 63;
    int w = t >> 6;
    int row0 = blockIdx.x * 64;

    int colE = (w & 1) * 64 + lane;
    float wcol[16];
#pragma unroll
    for (int k = 0; k < 16; ++k) wcol[k] = Wenc[k * 128 + colE];
    float bcol = benc[colE];
    int rof = __builtin_amdgcn_readfirstlane(t >> 7);

#pragma unroll
    for (int i = 0; i < 32; ++i) {
        int r = 2 * i + rof;
        int grow = row0 + r;
        if (grow >= M) grow = M - 1;
        const float* fr = feat + (size_t)grow * 16;
        float acc = bcol;
#pragma unroll
        for (int k = 0; k < 16; ++k)
            acc = fmaf(fr[k], wcol[k], acc);
        Hs[r * 136 + colE] = f2bfu(fmaxf(acc, 0.f));
    }
    __syncthreads();

    {
        int r = t >> 2, q = t & 3;
        float s = 0.f, s2 = 0.f;
#pragma unroll
        for (int c = q * 32; c < q * 32 + 32; ++c) {
            float v = bfu2f(Hs[r * 136 + c]);
            s += v;
            s2 = fmaf(v, v, s2);
        }
        red_s[t] = s;
        red_q[t] = s2;
    }
    __syncthreads();
    if (t < 64) {
        float s  = red_s[t * 4] + red_s[t * 4 + 1] + red_s[t * 4 + 2] + red_s[t * 4 + 3];
        float s2 = red_q[t * 4] + red_q[t * 4 + 1] + red_q[t * 4 + 2] + red_q[t * 4 + 3];
        float mu = s * (1.f / 128.f);
        float var = s2 * (1.f / 128.f) - mu * mu;
        s_mu[t] = mu;
        s_inv[t] = rsqrtf(var + LN_EPS);
    }
    __syncthreads();

    {
        float gc = g[colE], bc = beta[colE];
#pragma unroll
        for (int i = 0; i < 32; ++i) {
            int r = 2 * i + rof;
            float v = bfu2f(Hs[r * 136 + colE]);
            Hs[r * 136 + colE] = f2bfu((v - s_mu[r]) * s_inv[r] * gc + bc);
        }
    }
    __syncthreads();

    int kq = lane >> 4;
    int ln = lane & 15;
    int wcol0 = w * 128;

    bf16x8 bfr[4][4];
#pragma unroll
    for (int ks = 0; ks < 4; ++ks)
#pragma unroll
        for (int nt = 0; nt < 4; ++nt) {
            const uint4* p = (const uint4*)&Hs[(nt * 16 + ln) * 136 + ks * 32 + kq * 8];
            bfr[ks][nt] = __builtin_bit_cast(bf16x8, *p);
        }

#pragma unroll
    for (int mt = 0; mt < 8; ++mt) {
        int colA = wcol0 + mt * 16 + ln;
        bf16x8 afr[4];
#pragma unroll
        for (int ks = 0; ks < 4; ++ks)
            afr[ks] = *(const bf16x8*)(Apack + ((size_t)(ks * 4 + kq) * 512 + colA) * 8);

        f32x4 acc[4];
#pragma unroll
        for (int nt = 0; nt < 4; ++nt) {
            f32x4 z = {0.f, 0.f, 0.f, 0.f};
            acc[nt] = z;
        }
#pragma unroll
        for (int ks = 0; ks < 4; ++ks)
#pragma unroll
            for (int nt = 0; nt < 4; ++nt)
                acc[nt] = __builtin_amdgcn_mfma_f32_16x16x32_bf16(
                    afr[ks], bfr[ks][nt], acc[nt], 0, 0, 0);

        int col = wcol0 + mt * 16 + kq * 4;
        float4 bb = *(const float4*)(bproj + col);
#pragma unroll
        for (int nt = 0; nt < 4; ++nt) {
            int node = row0 + nt * 16 + ln;
            if (node < M) {
                ushort4 o;
                o.x = f2bfu(acc[nt][0] + bb.x);
                o.y = f2bfu(acc[nt][1] + bb.y);
                o.z = f2bfu(acc[nt][2] + bb.z);
                o.w = f2bfu(acc[nt][3] + bb.w);
                *(ushort4*)(out + (size_t)node * 512 + col) = o;
            }
        }
    }
}

// ---------------------------------------------------------------------------
// final GEMM (MFMA): C[M,128] = relu(A[M,128] @ Wp + bp), in place (A == C)
// ---------------------------------------------------------------------------
__global__ __launch_bounds__(256) void final_gemm_kernel(
    const float* __restrict__ A, const bf16_t* __restrict__ Ppack,
    const float* __restrict__ bp, float* __restrict__ C, int M)
{
    __shared__ unsigned short Hs[64 * 136];
    int t = threadIdx.x;
    int lane = t & 63;
    int w = t >> 6;
    int row0 = blockIdx.x * 64;

#pragma unroll
    for (int i = 0; i < 8; ++i) {
        int f4 = i * 256 + t;
        int r = f4 >> 5;
        int c4 = (f4 & 31) * 4;
        float4 v = make_float4(0.f, 0.f, 0.f, 0.f);
        if (row0 + r < M)
            v = ((const float4*)(A + (size_t)(row0 + r) * 128))[f4 & 31];
        ushort4 o;
        o.x = f2bfu(v.x); o.y = f2bfu(v.y); o.z = f2bfu(v.z); o.w = f2bfu(v.w);
        *(ushort4*)&Hs[r * 136 + c4] = o;
    }
    __syncthreads();

    int kq = lane >> 4;
    int ln = lane & 15;

    f32x4 acc[2][4];
#pragma unroll
    for (int mt = 0; mt < 2; ++mt)
#pragma unroll
        for (int nt = 0; nt < 4; ++nt) {
            f32x4 z = {0.f, 0.f, 0.f, 0.f};
            acc[mt][nt] = z;
        }

#pragma unroll
    for (int ks = 0; ks < 4; ++ks) {
        bf16x8 bfr[4];
#pragma unroll
        for (int nt = 0; nt < 4; ++nt) {
            const uint4* p = (const uint4*)&Hs[(nt * 16 + ln) * 136 + ks * 32 + kq * 8];
            bfr[nt] = __builtin_bit_cast(bf16x8, *p);
        }
        bf16x8 afr[2];
#pragma unroll
        for (int mt = 0; mt < 2; ++mt) {
            int colA = w * 32 + mt * 16 + ln;
            afr[mt] = *(const bf16x8*)(Ppack + ((size_t)(ks * 4 + kq) * 128 + colA) * 8);
        }
#pragma unroll
        for (int mt = 0; mt < 2; ++mt)
#pragma unroll
            for (int nt = 0; nt < 4; ++nt)
                acc[mt][nt] = __builtin_amdgcn_mfma_f32_16x16x32_bf16(
                    afr[mt], bfr[nt], acc[mt][nt], 0, 0, 0);
    }

#pragma unroll
    for (int mt = 0; mt < 2; ++mt) {
        int col = w * 32 + mt * 16 + kq * 4;
        float4 bb = *(const float4*)(bp + col);
#pragma unroll
        for (int nt = 0; nt < 4; ++nt) {
            int node = row0 + nt * 16 + ln;
            if (node < M) {
                float4 o;
                o.x = fmaxf(acc[mt][nt][0] + bb.x, 0.f);
                o.y = fmaxf(acc[mt][nt][1] + bb.y, 0.f);
                o.z = fmaxf(acc[mt][nt][2] + bb.z, 0.f);
                o.w = fmaxf(acc[mt][nt][3] + bb.w, 0.f);
                *(float4*)(C + (size_t)node * 128 + col) = o;
            }
        }
    }
}

// ---------------------------------------------------------------------------
// FUSED score + segment-softmax + aggregate (online softmax, no atomics).
// One wave per dst node. Lane l owns the 8 contiguous elements o=l*8 of the
// 512-wide (head-major) projected rows; lanes l>>4 form one head group.
// Per edge: gather fs[src] row once, leaky-relu dot vs attn (butterfly over
// the 16-lane head group), flash-style running (m, sum, acc) update.
// Epilogue: normalize, fold 4 heads via shfl_xor(16/32), coalesced store.
// ---------------------------------------------------------------------------
__global__ __launch_bounds__(256) void softagg_kernel(
    const unsigned short* __restrict__ fs, const unsigned short* __restrict__ fdp,
    const float* __restrict__ attn, const int* __restrict__ src,
    const int* __restrict__ offs, const int* __restrict__ deg,
    const int* __restrict__ eidx, float* __restrict__ out)
{
    int d = blockIdx.x * 4 + (threadIdx.x >> 6);
    if (d >= NE_N) return;
    int l = threadIdx.x & 63;
    int r0 = offs[d];
    int n = deg[d];
    int o = l * 8;

    // per-lane fd fragment + attn fragment (registers, loop-invariant)
    uint4 fv = *(const uint4*)(fdp + (size_t)d * 512 + o);
    float fdv[8] = { blo(fv.x), bhi(fv.x), blo(fv.y), bhi(fv.y),
                     blo(fv.z), bhi(fv.z), blo(fv.w), bhi(fv.w) };
    float4 w0 = *(const float4*)(attn + o);
    float4 w1 = *(const float4*)(attn + o + 4);
    float wv[8] = { w0.x, w0.y, w0.z, w0.w, w1.x, w1.y, w1.z, w1.w };

    float m = -1e30f, sm = 0.f;
    float acc[8];
#pragma unroll
    for (int j = 0; j < 8; ++j) acc[j] = 0.f;

    for (int base = 0; base < n; base += 64) {
        int cnt = min(n - base, 64);
        int sl = 0;
        if (l < cnt) sl = src[eidx[r0 + base + l]];   // batched index fetch
        for (int i = 0; i < cnt; ++i) {
            int s = __shfl(sl, i, 64);
            uint4 a = *(const uint4*)(fs + (size_t)s * 512 + o);
            float fsv[8] = { blo(a.x), bhi(a.x), blo(a.y), bhi(a.y),
                             blo(a.z), bhi(a.z), blo(a.w), bhi(a.w) };
            float p = 0.f;
#pragma unroll
            for (int j = 0; j < 8; ++j)
                p = fmaf(lrelu(fsv[j] + fdv[j]), wv[j], p);
#pragma unroll
            for (int mk = 1; mk < 16; mk <<= 1)
                p += __shfl_xor(p, mk, 64);
            // online softmax (p is uniform within the 16-lane head group)
            float mn = fmaxf(m, p);
            float c  = __expf(m - mn);
            float av = __expf(p - mn);
            sm = sm * c + av;
            m = mn;
#pragma unroll
            for (int j = 0; j < 8; ++j)
                acc[j] = fmaf(av, fsv[j], acc[j] * c);
        }
    }

    float inv = (n > 0) ? 0.25f / sm : 0.f;
#pragma unroll
    for (int j = 0; j < 8; ++j) {
        float v = acc[j] * inv;
        v += __shfl_xor(v, 16, 64);     // fold heads 0<->1, 2<->3
        v += __shfl_xor(v, 32, 64);     // fold pairs
        acc[j] = v;
    }
    if (l < 16) {
        float4 o0 = make_float4(acc[0], acc[1], acc[2], acc[3]);
        float4 o1 = make_float4(acc[4], acc[5], acc[6], acc[7]);
        *(float4*)(out + (size_t)d * 128 + l * 8) = o0;
        *(float4*)(out + (size_t)d * 128 + l * 8 + 4) = o1;
    }
}

// ---------------------------------------------------------------------------
extern "C" void kernel_launch(void* const* d_in, const int* in_sizes, int n_in,
                              void* d_out, int out_size, void* d_ws, size_t ws_size,
                              hipStream_t stream)
{
    const float* v_feat = (const float*)d_in[0];
    const float* e_feat = (const float*)d_in[1];
    const float* Wv     = (const float*)d_in[2];
    const float* bv     = (const float*)d_in[3];
    const float* gv     = (const float*)d_in[4];
    const float* betav  = (const float*)d_in[5];
    const float* We     = (const float*)d_in[6];
    const float* be     = (const float*)d_in[7];
    const float* ge     = (const float*)d_in[8];
    const float* betae  = (const float*)d_in[9];
    const float* Wsrc   = (const float*)d_in[10];
    const float* bsrc   = (const float*)d_in[11];
    const float* Wdst   = (const float*)d_in[12];
    const float* bdst   = (const float*)d_in[13];
    const float* attn   = (const float*)d_in[14];
    const float* Wp     = (const float*)d_in[15];
    const float* bp     = (const float*)d_in[16];
    const int*   src    = (const int*)d_in[17];
    const int*   dst    = (const int*)d_in[18];
    float* out = (float*)d_out;

    unsigned short* fs = (unsigned short*)d_ws;
    unsigned short* fd = fs + (size_t)NV * 512;
    int* deg    = (int*)(fd + (size_t)NE_N * 512);
    int* offs   = deg + NE_N;
    int* cursor = offs + NE_N;
    int* bsum   = cursor + NE_N;
    int* eidx   = bsum + 512;
    bf16_t* pS  = (bf16_t*)(eidx + NEDGE);
    bf16_t* pD  = pS + 65536;
    bf16_t* pP  = pD + 65536;

    const int NB_SCAN = (NE_N + 255) / 256;   // 391

    prep_kernel<<<72, 256, 0, stream>>>(Wsrc, Wdst, Wp, pS, pD, pP);

    // CSR build
    hipMemsetAsync(deg, 0, (size_t)NE_N * sizeof(int), stream);
    count_kernel<<<(NEDGE + 255) / 256, 256, 0, stream>>>(dst, deg);
    scan1_kernel<<<NB_SCAN, 256, 0, stream>>>(deg, offs, bsum);
    scan2_kernel<<<1, 512, 0, stream>>>(bsum, NB_SCAN);
    scan3_kernel<<<NB_SCAN, 256, 0, stream>>>(offs, bsum, cursor);
    scatter_kernel<<<(NEDGE + 255) / 256, 256, 0, stream>>>(dst, cursor, eidx);

    enc_proj_kernel<<<1563, 256, 0, stream>>>(v_feat, Wv, bv, gv, betav,
                                              pS, bsrc, fs, NV);
    enc_proj_kernel<<<1563, 256, 0, stream>>>(e_feat, We, be, ge, betae,
                                              pD, bdst, fd, NE_N);

    softagg_kernel<<<NE_N / 4, 256, 0, stream>>>(fs, fd, attn, src, offs, deg,
                                                 eidx, out);

    final_gemm_kernel<<<1563, 256, 0, stream>>>(out, pP, bp, out, NE_N);
}

// Round 7
// 372.077 us; speedup vs baseline: 2.3556x; 1.0441x over previous
//
#include <hip/hip_runtime.h>
#include <hip/hip_bf16.h>
#include <math.h>

#define NV 100000
#define NE_N 100000
#define NEDGE 250000
#define NEG 0.2f
#define LN_EPS 1e-5f

typedef __bf16 bf16_t;
typedef __bf16 bf16x8 __attribute__((ext_vector_type(8)));
typedef float f32x4 __attribute__((ext_vector_type(4)));

__device__ inline unsigned short f2bfu(float f) {
    return __builtin_bit_cast(unsigned short, (__bf16)f);
}
__device__ inline float bfu2f(unsigned short u) {
    return (float)__builtin_bit_cast(__bf16, u);
}
__device__ inline float blo(unsigned w) { return __uint_as_float(w << 16); }
__device__ inline float bhi(unsigned w) { return __uint_as_float(w & 0xffff0000u); }
__device__ inline float lrelu(float x) { return x > 0.f ? x : NEG * x; }

// ---------------------------------------------------------------------------
// prep: pack W matrices into bf16 A-fragment order:
//   pack[((ksq)*N + col)*8 + j] = W[ksq*8 + j][col],  ksq = 0..15 (K=128)
// ---------------------------------------------------------------------------
__global__ __launch_bounds__(256) void prep_kernel(
    const float* __restrict__ Wsrc, const float* __restrict__ Wdst,
    const float* __restrict__ Wp, bf16_t* __restrict__ pS,
    bf16_t* __restrict__ pD, bf16_t* __restrict__ pP)
{
    int t = blockIdx.x * 256 + threadIdx.x;
    if (t < 8192) {
        int ksq = t >> 9, col = t & 511;
#pragma unroll
        for (int j = 0; j < 8; ++j)
            pS[(size_t)t * 8 + j] = (bf16_t)Wsrc[(ksq * 8 + j) * 512 + col];
    } else if (t < 16384) {
        int g = t - 8192;
        int ksq = g >> 9, col = g & 511;
#pragma unroll
        for (int j = 0; j < 8; ++j)
            pD[(size_t)g * 8 + j] = (bf16_t)Wdst[(ksq * 8 + j) * 512 + col];
    } else if (t < 18432) {
        int g = t - 16384;
        int ksq = g >> 7, col = g & 127;
#pragma unroll
        for (int j = 0; j < 8; ++j)
            pP[(size_t)g * 8 + j] = (bf16_t)Wp[(ksq * 8 + j) * 128 + col];
    }
}

// ---------------------------------------------------------------------------
// CSR build kernels
// ---------------------------------------------------------------------------
__global__ __launch_bounds__(256) void count_kernel(
    const int* __restrict__ dst, int* __restrict__ deg)
{
    int t = blockIdx.x * 256 + threadIdx.x;
    if (t < NEDGE) atomicAdd(&deg[dst[t]], 1);
}

__global__ __launch_bounds__(256) void scan1_kernel(
    const int* __restrict__ deg, int* __restrict__ offs, int* __restrict__ bsum)
{
    __shared__ int s[256];
    int i = blockIdx.x * 256 + threadIdx.x;
    int v = (i < NE_N) ? deg[i] : 0;
    s[threadIdx.x] = v;
    __syncthreads();
    for (int off = 1; off < 256; off <<= 1) {
        int t_ = (threadIdx.x >= off) ? s[threadIdx.x - off] : 0;
        __syncthreads();
        s[threadIdx.x] += t_;
        __syncthreads();
    }
    if (i < NE_N) offs[i] = s[threadIdx.x] - v;   // exclusive within block
    if (threadIdx.x == 255) bsum[blockIdx.x] = s[255];
}

__global__ __launch_bounds__(512) void scan2_kernel(int* __restrict__ bsum, int nb)
{
    __shared__ int s[512];
    int t = threadIdx.x;
    int v = (t < nb) ? bsum[t] : 0;
    s[t] = v;
    __syncthreads();
    for (int off = 1; off < 512; off <<= 1) {
        int t_ = (t >= off) ? s[t - off] : 0;
        __syncthreads();
        s[t] += t_;
        __syncthreads();
    }
    if (t < nb) bsum[t] = s[t] - v;               // exclusive
}

__global__ __launch_bounds__(256) void scan3_kernel(
    int* __restrict__ offs, const int* __restrict__ bsum, int* __restrict__ cursor)
{
    int i = blockIdx.x * 256 + threadIdx.x;
    if (i < NE_N) {
        int o = offs[i] + bsum[blockIdx.x];
        offs[i] = o;
        cursor[i] = o;
    }
}

__global__ __launch_bounds__(256) void scatter_kernel(
    const int* __restrict__ dst, int* __restrict__ cursor, int* __restrict__ eidx)
{
    int t = blockIdx.x * 256 + threadIdx.x;
    if (t < NEDGE) {
        int pos = atomicAdd(&cursor[dst[t]], 1);
        eidx[pos] = t;
    }
}

// ---------------------------------------------------------------------------
// Fused encoder + MFMA projection.
// Wave w owns output rows w*16..w*16+15 (all 512 cols). Its B-frags come
// from its OWN 16 Hs rows (loaded once to regs); those rows then become the
// wave's private staging buffer for coalesced 64B-line output stores.
// ---------------------------------------------------------------------------
__global__ __launch_bounds__(256, 6) void enc_proj_kernel(
    const float* __restrict__ feat,
    const float* __restrict__ Wenc, const float* __restrict__ benc,
    const float* __restrict__ g, const float* __restrict__ beta,
    const bf16_t* __restrict__ Apack, const float* __restrict__ bproj,
    unsigned short* __restrict__ out, int M)
{
    __shared__ unsigned short Hs[64 * 136];
    __shared__ float red_s[256], red_q[256];
    __shared__ float s_mu[64], s_inv[64];

    int t = threadIdx.x;
    int lane = t & 63;
    int w = t >> 6;
    int row0 = blockIdx.x * 64;

    // ---- encoder: thread owns col, 32 rows (stride 2); feat via scalar loads
    int colE = (w & 1) * 64 + lane;
    float wcol[16];
#pragma unroll
    for (int k = 0; k < 16; ++k) wcol[k] = Wenc[k * 128 + colE];
    float bcol = benc[colE];
    int rof = __builtin_amdgcn_readfirstlane(t >> 7);

#pragma unroll
    for (int i = 0; i < 32; ++i) {
        int r = 2 * i + rof;
        int grow = row0 + r;
        if (grow >= M) grow = M - 1;
        const float* fr = feat + (size_t)grow * 16;
        float acc = bcol;
#pragma unroll
        for (int k = 0; k < 16; ++k)
            acc = fmaf(fr[k], wcol[k], acc);
        Hs[r * 136 + colE] = f2bfu(fmaxf(acc, 0.f));
    }
    __syncthreads();

    // ---- layernorm stats
    {
        int r = t >> 2, q = t & 3;
        float s = 0.f, s2 = 0.f;
#pragma unroll
        for (int c = q * 32; c < q * 32 + 32; ++c) {
            float v = bfu2f(Hs[r * 136 + c]);
            s += v;
            s2 = fmaf(v, v, s2);
        }
        red_s[t] = s;
        red_q[t] = s2;
    }
    __syncthreads();
    if (t < 64) {
        float s  = red_s[t * 4] + red_s[t * 4 + 1] + red_s[t * 4 + 2] + red_s[t * 4 + 3];
        float s2 = red_q[t * 4] + red_q[t * 4 + 1] + red_q[t * 4 + 2] + red_q[t * 4 + 3];
        float mu = s * (1.f / 128.f);
        float var = s2 * (1.f / 128.f) - mu * mu;
        s_mu[t] = mu;
        s_inv[t] = rsqrtf(var + LN_EPS);
    }
    __syncthreads();

    // ---- normalize in place
    {
        float gc = g[colE], bc = beta[colE];
#pragma unroll
        for (int i = 0; i < 32; ++i) {
            int r = 2 * i + rof;
            float v = bfu2f(Hs[r * 136 + colE]);
            Hs[r * 136 + colE] = f2bfu((v - s_mu[r]) * s_inv[r] * gc + bc);
        }
    }
    __syncthreads();

    // ---- MFMA: wave w computes rows w*16..+15, all 512 cols.
    int kq = lane >> 4;
    int ln = lane & 15;

    // B-frags from the wave's own 16 rows (then those rows are reusable)
    bf16x8 bfr[4];
#pragma unroll
    for (int ks = 0; ks < 4; ++ks) {
        const uint4* p = (const uint4*)&Hs[(w * 16 + ln) * 136 + ks * 32 + kq * 8];
        bfr[ks] = __builtin_bit_cast(bf16x8, *p);
    }
    // wave-private staging = the wave's own Hs rows (only this wave reads them)
    unsigned short* stag = Hs + w * 16 * 136;
    int node = row0 + w * 16 + ln;
    bool wr = node < M;

#pragma unroll
    for (int pass = 0; pass < 4; ++pass) {
        int colp = pass * 128;
#pragma unroll
        for (int mt = 0; mt < 8; ++mt) {
            int colA = colp + mt * 16 + ln;
            bf16x8 afr[4];
#pragma unroll
            for (int ks = 0; ks < 4; ++ks)
                afr[ks] = *(const bf16x8*)(Apack + ((size_t)(ks * 4 + kq) * 512 + colA) * 8);

            f32x4 acc = {0.f, 0.f, 0.f, 0.f};
#pragma unroll
            for (int ks = 0; ks < 4; ++ks)
                acc = __builtin_amdgcn_mfma_f32_16x16x32_bf16(afr[ks], bfr[ks], acc, 0, 0, 0);

            // lane holds node = row0+w*16+ln(C-col), cols mt*16+kq*4..+3 (C-rows)
            int col = colp + mt * 16 + kq * 4;
            float4 bb = *(const float4*)(bproj + col);
            ushort4 o;
            o.x = f2bfu(acc[0] + bb.x);
            o.y = f2bfu(acc[1] + bb.y);
            o.z = f2bfu(acc[2] + bb.z);
            o.w = f2bfu(acc[3] + bb.w);
            *(ushort4*)&stag[ln * 136 + mt * 16 + kq * 4] = o;
        }
        // write out this pass's 16 rows x 128 cols with full-line stores:
        // instr i: lane (ln,kq) -> 16B at row ln, col i*32+kq*8  (16 rows x 64B)
#pragma unroll
        for (int i = 0; i < 4; ++i) {
            uint4 v = *(const uint4*)&stag[ln * 136 + i * 32 + kq * 8];
            if (wr)
                *(uint4*)(out + (size_t)node * 512 + colp + i * 32 + kq * 8) = v;
        }
    }
}

// ---------------------------------------------------------------------------
// final GEMM (MFMA): C[M,128] = relu(A[M,128] @ Wp + bp), in place (A == C)
// ---------------------------------------------------------------------------
__global__ __launch_bounds__(256) void final_gemm_kernel(
    const float* __restrict__ A, const bf16_t* __restrict__ Ppack,
    const float* __restrict__ bp, float* __restrict__ C, int M)
{
    __shared__ unsigned short Hs[64 * 136];
    int t = threadIdx.x;
    int lane = t & 63;
    int w = t >> 6;
    int row0 = blockIdx.x * 64;

#pragma unroll
    for (int i = 0; i < 8; ++i) {
        int f4 = i * 256 + t;
        int r = f4 >> 5;
        int c4 = (f4 & 31) * 4;
        float4 v = make_float4(0.f, 0.f, 0.f, 0.f);
        if (row0 + r < M)
            v = ((const float4*)(A + (size_t)(row0 + r) * 128))[f4 & 31];
        ushort4 o;
        o.x = f2bfu(v.x); o.y = f2bfu(v.y); o.z = f2bfu(v.z); o.w = f2bfu(v.w);
        *(ushort4*)&Hs[r * 136 + c4] = o;
    }
    __syncthreads();

    int kq = lane >> 4;
    int ln = lane & 15;

    f32x4 acc[2][4];
#pragma unroll
    for (int mt = 0; mt < 2; ++mt)
#pragma unroll
        for (int nt = 0; nt < 4; ++nt) {
            f32x4 z = {0.f, 0.f, 0.f, 0.f};
            acc[mt][nt] = z;
        }

#pragma unroll
    for (int ks = 0; ks < 4; ++ks) {
        bf16x8 bfr[4];
#pragma unroll
        for (int nt = 0; nt < 4; ++nt) {
            const uint4* p = (const uint4*)&Hs[(nt * 16 + ln) * 136 + ks * 32 + kq * 8];
            bfr[nt] = __builtin_bit_cast(bf16x8, *p);
        }
        bf16x8 afr[2];
#pragma unroll
        for (int mt = 0; mt < 2; ++mt) {
            int colA = w * 32 + mt * 16 + ln;
            afr[mt] = *(const bf16x8*)(Ppack + ((size_t)(ks * 4 + kq) * 128 + colA) * 8);
        }
#pragma unroll
        for (int mt = 0; mt < 2; ++mt)
#pragma unroll
            for (int nt = 0; nt < 4; ++nt)
                acc[mt][nt] = __builtin_amdgcn_mfma_f32_16x16x32_bf16(
                    afr[mt], bfr[nt], acc[mt][nt], 0, 0, 0);
    }

#pragma unroll
    for (int mt = 0; mt < 2; ++mt) {
        int col = w * 32 + mt * 16 + kq * 4;
        float4 bb = *(const float4*)(bp + col);
#pragma unroll
        for (int nt = 0; nt < 4; ++nt) {
            int node = row0 + nt * 16 + ln;
            if (node < M) {
                float4 o;
                o.x = fmaxf(acc[mt][nt][0] + bb.x, 0.f);
                o.y = fmaxf(acc[mt][nt][1] + bb.y, 0.f);
                o.z = fmaxf(acc[mt][nt][2] + bb.z, 0.f);
                o.w = fmaxf(acc[mt][nt][3] + bb.w, 0.f);
                *(float4*)(C + (size_t)node * 128 + col) = o;
            }
        }
    }
}

// ---------------------------------------------------------------------------
// FUSED score + segment-softmax + aggregate (online softmax, no atomics).
// ---------------------------------------------------------------------------
__global__ __launch_bounds__(256) void softagg_kernel(
    const unsigned short* __restrict__ fs, const unsigned short* __restrict__ fdp,
    const float* __restrict__ attn, const int* __restrict__ src,
    const int* __restrict__ offs, const int* __restrict__ deg,
    const int* __restrict__ eidx, float* __restrict__ out)
{
    int d = blockIdx.x * 4 + (threadIdx.x >> 6);
    if (d >= NE_N) return;
    int l = threadIdx.x & 63;
    int r0 = offs[d];
    int n = deg[d];
    int o = l * 8;

    uint4 fv = *(const uint4*)(fdp + (size_t)d * 512 + o);
    float fdv[8] = { blo(fv.x), bhi(fv.x), blo(fv.y), bhi(fv.y),
                     blo(fv.z), bhi(fv.z), blo(fv.w), bhi(fv.w) };
    float4 w0 = *(const float4*)(attn + o);
    float4 w1 = *(const float4*)(attn + o + 4);
    float wv[8] = { w0.x, w0.y, w0.z, w0.w, w1.x, w1.y, w1.z, w1.w };

    float m = -1e30f, sm = 0.f;
    float acc[8];
#pragma unroll
    for (int j = 0; j < 8; ++j) acc[j] = 0.f;

    for (int base = 0; base < n; base += 64) {
        int cnt = min(n - base, 64);
        int sl = 0;
        if (l < cnt) sl = src[eidx[r0 + base + l]];
        for (int i = 0; i < cnt; ++i) {
            int s = __shfl(sl, i, 64);
            uint4 a = *(const uint4*)(fs + (size_t)s * 512 + o);
            float fsv[8] = { blo(a.x), bhi(a.x), blo(a.y), bhi(a.y),
                             blo(a.z), bhi(a.z), blo(a.w), bhi(a.w) };
            float p = 0.f;
#pragma unroll
            for (int j = 0; j < 8; ++j)
                p = fmaf(lrelu(fsv[j] + fdv[j]), wv[j], p);
#pragma unroll
            for (int mk = 1; mk < 16; mk <<= 1)
                p += __shfl_xor(p, mk, 64);
            float mn = fmaxf(m, p);
            float c  = __expf(m - mn);
            float av = __expf(p - mn);
            sm = sm * c + av;
            m = mn;
#pragma unroll
            for (int j = 0; j < 8; ++j)
                acc[j] = fmaf(av, fsv[j], acc[j] * c);
        }
    }

    float inv = (n > 0) ? 0.25f / sm : 0.f;
#pragma unroll
    for (int j = 0; j < 8; ++j) {
        float v = acc[j] * inv;
        v += __shfl_xor(v, 16, 64);
        v += __shfl_xor(v, 32, 64);
        acc[j] = v;
    }
    if (l < 16) {
        float4 o0 = make_float4(acc[0], acc[1], acc[2], acc[3]);
        float4 o1 = make_float4(acc[4], acc[5], acc[6], acc[7]);
        *(float4*)(out + (size_t)d * 128 + l * 8) = o0;
        *(float4*)(out + (size_t)d * 128 + l * 8 + 4) = o1;
    }
}

// ---------------------------------------------------------------------------
extern "C" void kernel_launch(void* const* d_in, const int* in_sizes, int n_in,
                              void* d_out, int out_size, void* d_ws, size_t ws_size,
                              hipStream_t stream)
{
    const float* v_feat = (const float*)d_in[0];
    const float* e_feat = (const float*)d_in[1];
    const float* Wv     = (const float*)d_in[2];
    const float* bv     = (const float*)d_in[3];
    const float* gv     = (const float*)d_in[4];
    const float* betav  = (const float*)d_in[5];
    const float* We     = (const float*)d_in[6];
    const float* be     = (const float*)d_in[7];
    const float* ge     = (const float*)d_in[8];
    const float* betae  = (const float*)d_in[9];
    const float* Wsrc   = (const float*)d_in[10];
    const float* bsrc   = (const float*)d_in[11];
    const float* Wdst   = (const float*)d_in[12];
    const float* bdst   = (const float*)d_in[13];
    const float* attn   = (const float*)d_in[14];
    const float* Wp     = (const float*)d_in[15];
    const float* bp     = (const float*)d_in[16];
    const int*   src    = (const int*)d_in[17];
    const int*   dst    = (const int*)d_in[18];
    float* out = (float*)d_out;

    unsigned short* fs = (unsigned short*)d_ws;
    unsigned short* fd = fs + (size_t)NV * 512;
    int* deg    = (int*)(fd + (size_t)NE_N * 512);
    int* offs   = deg + NE_N;
    int* cursor = offs + NE_N;
    int* bsum   = cursor + NE_N;
    int* eidx   = bsum + 512;
    bf16_t* pS  = (bf16_t*)(eidx + NEDGE);
    bf16_t* pD  = pS + 65536;
    bf16_t* pP  = pD + 65536;

    const int NB_SCAN = (NE_N + 255) / 256;   // 391

    prep_kernel<<<72, 256, 0, stream>>>(Wsrc, Wdst, Wp, pS, pD, pP);

    // CSR build
    hipMemsetAsync(deg, 0, (size_t)NE_N * sizeof(int), stream);
    count_kernel<<<(NEDGE + 255) / 256, 256, 0, stream>>>(dst, deg);
    scan1_kernel<<<NB_SCAN, 256, 0, stream>>>(deg, offs, bsum);
    scan2_kernel<<<1, 512, 0, stream>>>(bsum, NB_SCAN);
    scan3_kernel<<<NB_SCAN, 256, 0, stream>>>(offs, bsum, cursor);
    scatter_kernel<<<(NEDGE + 255) / 256, 256, 0, stream>>>(dst, cursor, eidx);

    enc_proj_kernel<<<1563, 256, 0, stream>>>(v_feat, Wv, bv, gv, betav,
                                              pS, bsrc, fs, NV);
    enc_proj_kernel<<<1563, 256, 0, stream>>>(e_feat, We, be, ge, betae,
                                              pD, bdst, fd, NE_N);

    softagg_kernel<<<NE_N / 4, 256, 0, stream>>>(fs, fd, attn, src, offs, deg,
                                                 eidx, out);

    final_gemm_kernel<<<1563, 256, 0, stream>>>(out, pP, bp, out, NE_N);
}